// Round 11
// baseline (433.116 us; speedup 1.0000x reference)
//
#include <hip/hip_runtime.h>

typedef __bf16 bf16;
typedef __bf16 bf16x4 __attribute__((ext_vector_type(4)));
typedef __bf16 bf16x8 __attribute__((ext_vector_type(8)));
typedef float f32x4 __attribute__((ext_vector_type(4)));
typedef short s16x4 __attribute__((ext_vector_type(4)));
typedef unsigned int u32;
typedef unsigned long long u64;

#define B_ 2
#define H_ 8
#define L_ 2048
#define D_ 128
#define F_ 128
#define QT 64
#define KT 64
#define NKT (L_ / KT)

// workspace layout (bytes)
#define WS_KB 0u            // Kb  : bf16 [b][k][16B-chunk swizzled], 1 MB
#define WS_VT (1u << 20)    // Vtb : bf16 [b][kt][g][f] linear (V read from L2), 1 MB
#define WS_MB (2u << 20)    // bits: u64 [b][q][kt], 1 MB

// LDS (R11, 3 blocks/CU): main sK0@0 sK1@16384 (16KB each, K only; V is L2-direct).
// epilogue: pOx@17408 f32[64][68]=17408 (one f-half per round);
//           sOh@34816 bf16[64][136]=17408 ; sO2t@0 bf16[128][136]=34816 ;
//           lws@52224 (512B). Total 52736 -> 160KB/52.7KB = 3 blocks/CU.
#define SMEM_BYTES 52736
#define LWS_OFF 52224
#define POX_OFF 17408
#define POX_STRIDE 68
#define SOH_OFF 34816
#define SOH_STRIDE 136
#define SO2_STRIDE 136

__device__ __forceinline__ void dma16(const void* g, void* l) {
    __builtin_amdgcn_global_load_lds(
        (const __attribute__((address_space(1))) u32*)g,
        (__attribute__((address_space(3))) u32*)l, 16, 0, 0);
}

__device__ __forceinline__ f32x4 mfma32(bf16x8 a, bf16x8 b, f32x4 c) {
    return __builtin_amdgcn_mfma_f32_16x16x32_bf16(a, b, c, 0, 0, 0);
}

__device__ __forceinline__ f32x4 mfma16(bf16x4 a, bf16x4 b, f32x4 c) {
#if __has_builtin(__builtin_amdgcn_mfma_f32_16x16x16_bf16)
    return __builtin_amdgcn_mfma_f32_16x16x16_bf16(a, b, c, 0, 0, 0);
#else
    s16x4 as = __builtin_bit_cast(s16x4, a);
    s16x4 bs = __builtin_bit_cast(s16x4, b);
    return __builtin_amdgcn_mfma_f32_16x16x16bf16_1k(as, bs, c, 0, 0, 0);
#endif
}

// guaranteed single-instruction exp2 (log2e is folded into g_s upstream)
__device__ __forceinline__ float fexp2(float x) {
#if __has_builtin(__builtin_amdgcn_exp2f)
    return __builtin_amdgcn_exp2f(x);
#else
    float r;
    asm("v_exp_f32 %0, %1" : "=v"(r) : "v"(x));
    return r;
#endif
}

// spread 16 bits to stride-4 positions of a u64 (bit i -> bit 4i)
__device__ __forceinline__ u64 spread4(u64 v) {
    v = (v | (v << 24)) & 0x000000ff000000ffULL;
    v = (v | (v << 12)) & 0x000f000f000f000fULL;
    v = (v | (v << 6))  & 0x0303030303030303ULL;
    v = (v | (v << 3))  & 0x1111111111111111ULL;
    return v;
}

// ---- SINGLE prep launch: mask bitpack (0..2047), K cvt+swz (2048..2303),
//      V [g][f] tiles (2304..2559), out zero (2560..2687).
__global__ __launch_bounds__(256)
void prep_one(const float* __restrict__ XK, const float* __restrict__ XV,
              const int* __restrict__ mask, bf16* __restrict__ Kb,
              bf16* __restrict__ Vtb, u64* __restrict__ bits,
              float* __restrict__ out)
{
    const int bid = blockIdx.x;
    const int tid = threadIdx.x;
    if (bid < 2048) {
        // mask bitpack: wave-iter W handles 256 ints (16B/lane); 4 ballots +
        // stride-4 spread on lanes 0..3 rebuild bits[W*4+q] (R8-verified).
        const int lane = tid & 63;
        const int wv   = bid * 4 + (tid >> 6);     // 0..8191
        const int4* m4 = (const int4*)mask;
        #pragma unroll
        for (int t = 0; t < 4; ++t) {
            int W = wv + t * 8192;                 // 0..32767
            int4 v = m4[(size_t)W * 64 + lane];
            int nib = (v.x != 0 ? 1 : 0) | (v.y != 0 ? 2 : 0)
                    | (v.z != 0 ? 4 : 0) | (v.w != 0 ? 8 : 0);
            u64 b0 = __ballot(nib & 1);
            u64 b1 = __ballot(nib & 2);
            u64 b2 = __ballot(nib & 4);
            u64 b3 = __ballot(nib & 8);
            if (lane < 4) {
                int sh = lane * 16;
                u64 w = spread4((b0 >> sh) & 0xFFFFull)
                      | (spread4((b1 >> sh) & 0xFFFFull) << 1)
                      | (spread4((b2 >> sh) & 0xFFFFull) << 2)
                      | (spread4((b3 >> sh) & 0xFFFFull) << 3);
                bits[(size_t)W * 4 + lane] = w;
            }
        }
    } else if (bid < 2304) {
        int gid = (bid - 2048) * 256 + tid;
        int row = gid >> 4;
        int j   = gid & 15;
        const float* src = XK + (size_t)row * 128 + j * 8;
        float4 v0 = *(const float4*)src;
        float4 v1 = *(const float4*)(src + 4);
        bf16x8 w;
        w[0] = (bf16)v0.x; w[1] = (bf16)v0.y; w[2] = (bf16)v0.z; w[3] = (bf16)v0.w;
        w[4] = (bf16)v1.x; w[5] = (bf16)v1.y; w[6] = (bf16)v1.z; w[7] = (bf16)v1.w;
        int jp = j ^ (row & 15);
        *(bf16x8*)(Kb + (size_t)row * 128 + jp * 8) = w;
    } else if (bid < 2560) {
        // V tiles [tile][g][f][4k] LINEAR (no swizzle): element (g,f,j) =
        // V[b][kt*64 + 4g + j][f]. attn reads 8B per lane at g*1024 + f*8
        // bytes -> lanes c=0..15 consecutive 8B -> coalesced from L2.
        int idx  = bid - 2304;
        int tile = idx >> 2;
        int fq   = idx & 3;
        int f    = fq * 32 + (tid & 31);
        int j    = tid >> 5;                  // 0..7 -> k = 8j..8j+7
        int bb   = tile >> 5, kt = tile & 31;
        const float* src = XV + ((size_t)(bb * L_ + kt * 64 + j * 8)) * F_ + f;
        bf16x4 w0, w1;
        #pragma unroll
        for (int jj = 0; jj < 4; ++jj) {
            w0[jj] = (bf16)src[(size_t)jj * F_];
            w1[jj] = (bf16)src[(size_t)(4 + jj) * F_];
        }
        bf16* outp = Vtb + (size_t)tile * 8192;
        *(bf16x4*)(outp + (2 * j) * 512 + f * 4) = w0;       // g = 2j
        *(bf16x4*)(outp + (2 * j + 1) * 512 + f * 4) = w1;   // g = 2j+1
    } else {
        // zero out[] (B*L*F floats = 131072 float4), replaces hipMemsetAsync
        float4* o4 = (float4*)out;
        int idx = (bid - 2560) * 256 + tid;        // 0..32767
        float4 z; z.x = 0.f; z.y = 0.f; z.z = 0.f; z.w = 0.f;
        #pragma unroll
        for (int t = 0; t < 4; ++t) o4[idx + t * 32768] = z;
    }
}

// ---- main fused kernel: 512 threads / 8 waves; wave = (kh, msel) ----
// R11: V is read directly from L2 (2MB Vtb is L2-resident; loads are
// coalesced-by-layout) -> LDS drops 66.5->52.7KB -> 3 blocks/CU, 24 waves/CU.
// DO NOT use the 2nd __launch_bounds__ arg (min-BLOCKS/CU semantics: R3 spill).
// waves_per_eu(6) caps VGPR ~80 >= the 64 this kernel needs (no-spill safe).
__global__ __launch_bounds__(512)
__attribute__((amdgpu_waves_per_eu(6)))
void attn_fused_kernel(const float* __restrict__ XQ, const bf16* __restrict__ Kb,
                       const bf16* __restrict__ Vtb, const u64* __restrict__ bits,
                       const float* __restrict__ WQ, const float* __restrict__ WK,
                       const float* __restrict__ WV, const float* __restrict__ Om,
                       float* __restrict__ out)
{
    __shared__ __align__(16) char smem[SMEM_BYTES];
    __shared__ __align__(16) float g_s[128];

    bf16* sK0 = (bf16*)smem;
    bf16* sK1 = (bf16*)(smem + 16384);
    float* lws = (float*)(smem + LWS_OFF);
    float* pOx = (float*)(smem + POX_OFF);     // epilogue: f32[64][68], per f-half
    bf16* sOh  = (bf16*)(smem + SOH_OFF);      // epilogue: bf16[64][136]
    bf16* sO2t = (bf16*)smem;                  // epilogue: bf16[128][136] (after pOx)

    const int tid  = threadIdx.x;
    const int wave = tid >> 6;        // 0..7
    const int lane = tid & 63;
    const int c    = lane & 15;
    const int quad = lane >> 4;
    const int qt = blockIdx.x, h = blockIdx.y, b = blockIdx.z;
    const int q0 = qt * QT;

    const int kh   = wave >> 2;       // k-half (32 k)
    const int msel = wave & 3;        // m-tile (16 m)
    const int fv  = tid & 127;        // epilogue staging
    const int grp = tid >> 7;         // 0..3

    if (tid < 128) {
        float wq = WQ[(h * D_ + tid) * D_ + tid];
        float wk = WK[(h * D_ + tid) * D_ + tid];
        // fold softmax scale AND log2(e): exp becomes a raw v_exp_f32
        g_s[tid] = wq * wk * 0.08838834764831845f * 1.4426950408889634f;
    }
    __syncthreads();

    const char* gKbase = (const char*)Kb + (size_t)(b * L_) * 256;
    const char* gVbase = (const char*)Vtb + (size_t)(b * NKT) * 16384;

    // DMA K tile 0 (V is not staged)
    #pragma unroll
    for (int i = 0; i < 2; ++i) dma16(gKbase + i * 8192 + tid * 16, (char*)sK0 + i * 8192 + tid * 16);

    const u64* mrow = bits + (size_t)(b * L_ + q0 + msel * 16 + c) * NKT;
    u64 mbc = mrow[0];                 // mask prefetch (one k-tile ahead)

    // hoisted loop-invariant byte offsets
    int koff[2][4];                    // LDS K fragment offsets
    #pragma unroll
    for (int kti = 0; kti < 2; ++kti)
        #pragma unroll
        for (int kc = 0; kc < 4; ++kc)
            koff[kti][kc] = ((((kh * 2 + kti) * 16 + c) * 128) + (((kc * 4 + quad) ^ c) * 8)) * 2;
    int voff[8][2];                    // GLOBAL V fragment offsets within a tile
    #pragma unroll
    for (int fi = 0; fi < 8; ++fi)
        #pragma unroll
        for (int kti = 0; kti < 2; ++kti) {
            int g = kh * 8 + kti * 4 + quad;
            voff[fi][kti] = g * 1024 + (fi * 16 + c) * 8;
        }

    // wave's Q m-tile as B-fragments (scaled by g, bf16), loop-invariant
    bf16x8 qfrag[4];
    {
        const float* qrow = XQ + (size_t)(b * L_ + q0 + msel * 16 + c) * D_;
        #pragma unroll
        for (int kc = 0; kc < 4; ++kc) {
            int d0 = kc * 32 + quad * 8;
            float4 v0 = *(const float4*)(qrow + d0);
            float4 v1 = *(const float4*)(qrow + d0 + 4);
            float4 g0 = *(const float4*)(g_s + d0);
            float4 g1 = *(const float4*)(g_s + d0 + 4);
            bf16x8 w;
            w[0] = (bf16)(v0.x * g0.x); w[1] = (bf16)(v0.y * g0.y);
            w[2] = (bf16)(v0.z * g0.z); w[3] = (bf16)(v0.w * g0.w);
            w[4] = (bf16)(v1.x * g1.x); w[5] = (bf16)(v1.y * g1.y);
            w[6] = (bf16)(v1.z * g1.z); w[7] = (bf16)(v1.w * g1.w);
            qfrag[kc] = w;
        }
    }

    f32x4 oacc[8];                     // partial O[m-tile msel][128 f] for kh's 32 k
    #pragma unroll
    for (int fi = 0; fi < 8; ++fi)
        #pragma unroll
        for (int r = 0; r < 4; ++r) oacc[fi][r] = 0.f;
    float lsum = 0.f;                  // per-lane: row m = msel*16+c, wave's k slice

    #pragma unroll 2
    for (int kt = 0; kt < NKT; ++kt) {
        const char* sK  = (kt & 1) ? (char*)sK1 : (char*)sK0;
        bf16* sKn = (kt & 1) ? sK0 : sK1;
        const char* gVt = gVbase + (size_t)kt * 16384;

        // A: all waves done reading buf[next]
        asm volatile("s_barrier" ::: "memory");

        u64 mb = mbc;

        if (kt + 1 < NKT) {
            const char* gk = gKbase + (size_t)(kt + 1) * 16384;
            #pragma unroll
            for (int i = 0; i < 2; ++i) dma16(gk + i * 8192 + tid * 16, (char*)sKn + i * 8192 + tid * 16);
            mbc = mrow[kt + 1];        // prefetch next tile's mask word
            // newest 3 = 1 mask + 2 next-DMA; prior-tile ops provably drained
            // (vmcnt retires in order; last iter's V loads were consumed)
            asm volatile("s_waitcnt vmcnt(3)" ::: "memory");
        } else {
            asm volatile("s_waitcnt vmcnt(0)" ::: "memory");
        }
        // B: tile kt resident
        asm volatile("s_barrier" ::: "memory");

        __builtin_amdgcn_s_setprio(1);

        // S^T = K @ Qg^T for wave's 2 k-tiles (kh*2+kti)
        f32x4 tacc[2];
        #pragma unroll
        for (int kti = 0; kti < 2; ++kti)
            #pragma unroll
            for (int r = 0; r < 4; ++r) tacc[kti][r] = 0.f;

        #pragma unroll
        for (int kti = 0; kti < 2; ++kti) {
            #pragma unroll
            for (int kc = 0; kc < 4; ++kc) {
                bf16x8 kfrag = *(const bf16x8*)(sK + koff[kti][kc]);
                tacc[kti] = mfma32(kfrag, qfrag[kc], tacc[kti]);
            }
        }

        // lane(c,quad) reg r = S^T[k = kh*32+kti*16+quad*4+r][m = msel*16+c]
        // -> exp2 (log2e folded) -> DIRECTLY the A-operand of 16x16x16 MFMA
        bf16x4 pfrag[2];
        #pragma unroll
        for (int kti = 0; kti < 2; ++kti) {
            #pragma unroll
            for (int r = 0; r < 4; ++r) {
                float p = ((mb >> (kh * 32 + kti * 16 + quad * 4 + r)) & 1ull)
                          ? fexp2(tacc[kti][r]) : 0.f;
                lsum += p;
                pfrag[kti][r] = (bf16)p;
            }
        }

        // O_partial += P @ V over wave's 32 k; V fragments straight from L2
        // (coalesced: lanes c=0..15 read consecutive 8B; 4x128B per instr)
        #pragma unroll
        for (int fi = 0; fi < 8; ++fi) {
            #pragma unroll
            for (int kti = 0; kti < 2; ++kti) {
                bf16x4 vfrag = *(const bf16x4*)(gVt + voff[fi][kti]);
                oacc[fi] = mfma16(pfrag[kti], vfrag, oacc[fi]);
            }
        }

        __builtin_amdgcn_s_setprio(0);
    }

    // publish per-wave row sums: lane c holds sum over wave's 32k after quad-reduce
    {
        float v = lsum;
        v += __shfl_xor(v, 16); v += __shfl_xor(v, 32);
        if (lane < 16) lws[wave * 16 + lane] = v;
    }
    if (tid < 128)
        g_s[tid] = WV[(h * F_ + tid) * F_ + tid];   // dv (g_s no longer needed)
    __syncthreads();   // main-loop LDS reads done; lws visible

    // normalizers for combiner waves (kh==0)
    float linv[4];
    if (kh == 0) {
        #pragma unroll
        for (int r = 0; r < 4; ++r) {
            int m16 = quad * 4 + r;
            linv[r] = 1.0f / (lws[msel * 16 + m16] + lws[(4 + msel) * 16 + m16]);
        }
    }

    // 2-way combine in two f-half rounds (pOx is only [64][68] f32)
    #pragma unroll
    for (int r2 = 0; r2 < 2; ++r2) {
        if (kh == 1) {
            #pragma unroll
            for (int fl = 0; fl < 4; ++fl)
                #pragma unroll
                for (int r = 0; r < 4; ++r)
                    pOx[(msel * 16 + quad * 4 + r) * POX_STRIDE + fl * 16 + c] = oacc[r2 * 4 + fl][r];
        }
        __syncthreads();
        if (kh == 0) {
            #pragma unroll
            for (int fl = 0; fl < 4; ++fl)
                #pragma unroll
                for (int r = 0; r < 4; ++r) {
                    int row = msel * 16 + quad * 4 + r;
                    float v = (oacc[r2 * 4 + fl][r] + pOx[row * POX_STRIDE + fl * 16 + c]) * linv[r];
                    sOh[row * SOH_STRIDE + (r2 * 4 + fl) * 16 + c] = (bf16)v;
                }
        }
        __syncthreads();
    }

    // stage O2^T: sO2t[f][f'] = O[h*128+f'][f] * dv[f']  (pOx region now dead)
    #pragma unroll
    for (int i = 0; i < 8; ++i) {
        int fp4 = grp * 32 + i * 4;
        bf16x4 w;
        #pragma unroll
        for (int j = 0; j < 4; ++j) {
            int x = fp4 + j;
            w[j] = (bf16)(Om[(h * F_ + x) * F_ + fv] * g_s[x]);
        }
        *(bf16x4*)(sO2t + fv * SO2_STRIDE + fp4) = w;
    }
    __syncthreads();

    // out_partial = Oh @ O2 : wave (pm = m-tile, pf = f-half)
    const int pm = wave & 3;
    const int pf = wave >> 2;
    bf16x8 afr[4];
    const bf16* ohrow = sOh + (pm * 16 + c) * SOH_STRIDE;
    #pragma unroll
    for (int kc = 0; kc < 4; ++kc)
        afr[kc] = *(const bf16x8*)(ohrow + kc * 32 + quad * 8);

    #pragma unroll
    for (int nt = 0; nt < 4; ++nt) {
        f32x4 pacc;
        #pragma unroll
        for (int r = 0; r < 4; ++r) pacc[r] = 0.f;
        const bf16* orow = sO2t + ((pf * 4 + nt) * 16 + c) * SO2_STRIDE;
        #pragma unroll
        for (int kc = 0; kc < 4; ++kc) {
            bf16x8 bfrag = *(const bf16x8*)(orow + kc * 32 + quad * 8);
            pacc = mfma32(afr[kc], bfrag, pacc);
        }
        #pragma unroll
        for (int r = 0; r < 4; ++r) {
            int qg = q0 + pm * 16 + quad * 4 + r;
            atomicAdd(out + ((size_t)(b * L_ + qg) * F_ + (pf * 4 + nt) * 16 + c), pacc[r]);
        }
    }
}

extern "C" void kernel_launch(void* const* d_in, const int* in_sizes, int n_in,
                              void* d_out, int out_size, void* d_ws, size_t ws_size,
                              hipStream_t stream) {
    const float* XQ   = (const float*)d_in[0];
    const float* XK   = (const float*)d_in[1];
    const float* XV   = (const float*)d_in[2];
    const int*   mask = (const int*)d_in[3];
    const float* WQ   = (const float*)d_in[4];
    const float* WK   = (const float*)d_in[5];
    const float* WV   = (const float*)d_in[6];
    const float* Om   = (const float*)d_in[7];
    float* out = (float*)d_out;

    char* ws = (char*)d_ws;
    bf16* Kb   = (bf16*)(ws + WS_KB);
    bf16* Vtb  = (bf16*)(ws + WS_VT);
    u64*  bits = (u64*)(ws + WS_MB);

    prep_one<<<2688, 256, 0, stream>>>(XK, XV, mask, Kb, Vtb, bits, out);

    dim3 grid(L_ / QT, H_, B_);
    attn_fused_kernel<<<grid, 512, 0, stream>>>(XQ, Kb, Vtb, bits, WQ, WK, WV, Om, out);
}

// Round 12
// 220.265 us; speedup vs baseline: 1.9663x; 1.9663x over previous
//
#include <hip/hip_runtime.h>

typedef __bf16 bf16;
typedef __bf16 bf16x4 __attribute__((ext_vector_type(4)));
typedef __bf16 bf16x8 __attribute__((ext_vector_type(8)));
typedef float f32x4 __attribute__((ext_vector_type(4)));
typedef short s16x4 __attribute__((ext_vector_type(4)));
typedef unsigned int u32;
typedef unsigned long long u64;

#define B_ 2
#define H_ 8
#define L_ 2048
#define D_ 128
#define F_ 128
#define QT 64
#define KT 64
#define NKT (L_ / KT)

// workspace layout (bytes)
#define WS_KB 0u            // Kb  : bf16 [b][k][16B-chunk swizzled], 1 MB
#define WS_VT (1u << 20)    // Vtb : bf16 [b][kt][g][f] linear (V read from L2), 1 MB
#define WS_MB (2u << 20)    // bits: u64 [b][q][kt], 1 MB

// LDS (3 blocks/CU): main sK0@0 sK1@16384 (16KB each, K only; V is L2-direct).
// epilogue: pOx@17408 f32[64][68]=17408 (one f-half per round);
//           sOh@34816 bf16[64][136]=17408 ; sO2t@0 bf16[128][136]=34816 ;
//           lws@52224 (512B). Total 52736 -> 160KB/52.7KB = 3 blocks/CU.
#define SMEM_BYTES 52736
#define LWS_OFF 52224
#define POX_OFF 17408
#define POX_STRIDE 68
#define SOH_OFF 34816
#define SOH_STRIDE 136
#define SO2_STRIDE 136

__device__ __forceinline__ void dma16(const void* g, void* l) {
    __builtin_amdgcn_global_load_lds(
        (const __attribute__((address_space(1))) u32*)g,
        (__attribute__((address_space(3))) u32*)l, 16, 0, 0);
}

__device__ __forceinline__ f32x4 mfma32(bf16x8 a, bf16x8 b, f32x4 c) {
    return __builtin_amdgcn_mfma_f32_16x16x32_bf16(a, b, c, 0, 0, 0);
}

__device__ __forceinline__ f32x4 mfma16(bf16x4 a, bf16x4 b, f32x4 c) {
#if __has_builtin(__builtin_amdgcn_mfma_f32_16x16x16_bf16)
    return __builtin_amdgcn_mfma_f32_16x16x16_bf16(a, b, c, 0, 0, 0);
#else
    s16x4 as = __builtin_bit_cast(s16x4, a);
    s16x4 bs = __builtin_bit_cast(s16x4, b);
    return __builtin_amdgcn_mfma_f32_16x16x16bf16_1k(as, bs, c, 0, 0, 0);
#endif
}

// guaranteed single-instruction exp2 (log2e is folded into g_s upstream)
__device__ __forceinline__ float fexp2(float x) {
#if __has_builtin(__builtin_amdgcn_exp2f)
    return __builtin_amdgcn_exp2f(x);
#else
    float r;
    asm("v_exp_f32 %0, %1" : "=v"(r) : "v"(x));
    return r;
#endif
}

// spread 16 bits to stride-4 positions of a u64 (bit i -> bit 4i)
__device__ __forceinline__ u64 spread4(u64 v) {
    v = (v | (v << 24)) & 0x000000ff000000ffULL;
    v = (v | (v << 12)) & 0x000f000f000f000fULL;
    v = (v | (v << 6))  & 0x0303030303030303ULL;
    v = (v | (v << 3))  & 0x1111111111111111ULL;
    return v;
}

// ---- SINGLE prep launch: mask bitpack (0..2047), K cvt+swz (2048..2303),
//      V [g][f] tiles (2304..2559), out zero (2560..2687).
__global__ __launch_bounds__(256)
void prep_one(const float* __restrict__ XK, const float* __restrict__ XV,
              const int* __restrict__ mask, bf16* __restrict__ Kb,
              bf16* __restrict__ Vtb, u64* __restrict__ bits,
              float* __restrict__ out)
{
    const int bid = blockIdx.x;
    const int tid = threadIdx.x;
    if (bid < 2048) {
        // mask bitpack: wave-iter W handles 256 ints (16B/lane); 4 ballots +
        // stride-4 spread on lanes 0..3 rebuild bits[W*4+q] (R8-verified).
        const int lane = tid & 63;
        const int wv   = bid * 4 + (tid >> 6);     // 0..8191
        const int4* m4 = (const int4*)mask;
        #pragma unroll
        for (int t = 0; t < 4; ++t) {
            int W = wv + t * 8192;                 // 0..32767
            int4 v = m4[(size_t)W * 64 + lane];
            int nib = (v.x != 0 ? 1 : 0) | (v.y != 0 ? 2 : 0)
                    | (v.z != 0 ? 4 : 0) | (v.w != 0 ? 8 : 0);
            u64 b0 = __ballot(nib & 1);
            u64 b1 = __ballot(nib & 2);
            u64 b2 = __ballot(nib & 4);
            u64 b3 = __ballot(nib & 8);
            if (lane < 4) {
                int sh = lane * 16;
                u64 w = spread4((b0 >> sh) & 0xFFFFull)
                      | (spread4((b1 >> sh) & 0xFFFFull) << 1)
                      | (spread4((b2 >> sh) & 0xFFFFull) << 2)
                      | (spread4((b3 >> sh) & 0xFFFFull) << 3);
                bits[(size_t)W * 4 + lane] = w;
            }
        }
    } else if (bid < 2304) {
        int gid = (bid - 2048) * 256 + tid;
        int row = gid >> 4;
        int j   = gid & 15;
        const float* src = XK + (size_t)row * 128 + j * 8;
        float4 v0 = *(const float4*)src;
        float4 v1 = *(const float4*)(src + 4);
        bf16x8 w;
        w[0] = (bf16)v0.x; w[1] = (bf16)v0.y; w[2] = (bf16)v0.z; w[3] = (bf16)v0.w;
        w[4] = (bf16)v1.x; w[5] = (bf16)v1.y; w[6] = (bf16)v1.z; w[7] = (bf16)v1.w;
        int jp = j ^ (row & 15);
        *(bf16x8*)(Kb + (size_t)row * 128 + jp * 8) = w;
    } else if (bid < 2560) {
        // V tiles [tile][g][f][4k] LINEAR (no swizzle): element (g,f,j) =
        // V[b][kt*64 + 4g + j][f]. attn reads 8B per lane at g*1024 + f*8
        // bytes -> lanes c=0..15 consecutive 8B -> coalesced from L2.
        int idx  = bid - 2304;
        int tile = idx >> 2;
        int fq   = idx & 3;
        int f    = fq * 32 + (tid & 31);
        int j    = tid >> 5;                  // 0..7 -> k = 8j..8j+7
        int bb   = tile >> 5, kt = tile & 31;
        const float* src = XV + ((size_t)(bb * L_ + kt * 64 + j * 8)) * F_ + f;
        bf16x4 w0, w1;
        #pragma unroll
        for (int jj = 0; jj < 4; ++jj) {
            w0[jj] = (bf16)src[(size_t)jj * F_];
            w1[jj] = (bf16)src[(size_t)(4 + jj) * F_];
        }
        bf16* outp = Vtb + (size_t)tile * 8192;
        *(bf16x4*)(outp + (2 * j) * 512 + f * 4) = w0;       // g = 2j
        *(bf16x4*)(outp + (2 * j + 1) * 512 + f * 4) = w1;   // g = 2j+1
    } else {
        // zero out[] (B*L*F floats = 131072 float4), replaces hipMemsetAsync
        float4* o4 = (float4*)out;
        int idx = (bid - 2560) * 256 + tid;        // 0..32767
        float4 z; z.x = 0.f; z.y = 0.f; z.z = 0.f; z.w = 0.f;
        #pragma unroll
        for (int t = 0; t < 4; ++t) o4[idx + t * 32768] = z;
    }
}

// ---- main fused kernel: 512 threads / 8 waves; wave = (kh, msel) ----
// V read directly from L2 (2MB Vtb L2-resident, coalesced-by-layout);
// LDS 52.7KB -> 3 blocks/CU possible with VGPR<=85.
// REGISTER-CAP RULE (3 strikes: R3, R4, R11): NO __launch_bounds__ 2nd arg,
// NO waves_per_eu above (4,4) -- any cap below the ~56-reg live state spills
// oacc to scratch (R11: VGPR 40, WRITE 336MB, 355us). No attribute at all
// gives VGPR 64 (R0-R6) and lets HW occupancy follow LDS: 3 blocks/CU.
__global__ __launch_bounds__(512)
void attn_fused_kernel(const float* __restrict__ XQ, const bf16* __restrict__ Kb,
                       const bf16* __restrict__ Vtb, const u64* __restrict__ bits,
                       const float* __restrict__ WQ, const float* __restrict__ WK,
                       const float* __restrict__ WV, const float* __restrict__ Om,
                       float* __restrict__ out)
{
    __shared__ __align__(16) char smem[SMEM_BYTES];
    __shared__ __align__(16) float g_s[128];

    bf16* sK0 = (bf16*)smem;
    bf16* sK1 = (bf16*)(smem + 16384);
    float* lws = (float*)(smem + LWS_OFF);
    float* pOx = (float*)(smem + POX_OFF);     // epilogue: f32[64][68], per f-half
    bf16* sOh  = (bf16*)(smem + SOH_OFF);      // epilogue: bf16[64][136]
    bf16* sO2t = (bf16*)smem;                  // epilogue: bf16[128][136] (after pOx)

    const int tid  = threadIdx.x;
    const int wave = tid >> 6;        // 0..7
    const int lane = tid & 63;
    const int c    = lane & 15;
    const int quad = lane >> 4;
    const int qt = blockIdx.x, h = blockIdx.y, b = blockIdx.z;
    const int q0 = qt * QT;

    const int kh   = wave >> 2;       // k-half (32 k)
    const int msel = wave & 3;        // m-tile (16 m)
    const int fv  = tid & 127;        // epilogue staging
    const int grp = tid >> 7;         // 0..3

    if (tid < 128) {
        float wq = WQ[(h * D_ + tid) * D_ + tid];
        float wk = WK[(h * D_ + tid) * D_ + tid];
        // fold softmax scale AND log2(e): exp becomes a raw v_exp_f32
        g_s[tid] = wq * wk * 0.08838834764831845f * 1.4426950408889634f;
    }
    __syncthreads();

    const char* gKbase = (const char*)Kb + (size_t)(b * L_) * 256;
    const char* gVbase = (const char*)Vtb + (size_t)(b * NKT) * 16384;

    // DMA K tile 0 (V is not staged)
    #pragma unroll
    for (int i = 0; i < 2; ++i) dma16(gKbase + i * 8192 + tid * 16, (char*)sK0 + i * 8192 + tid * 16);

    const u64* mrow = bits + (size_t)(b * L_ + q0 + msel * 16 + c) * NKT;
    u64 mbc = mrow[0];                 // mask prefetch (one k-tile ahead)

    // hoisted loop-invariant byte offsets
    int koff[2][4];                    // LDS K fragment offsets
    #pragma unroll
    for (int kti = 0; kti < 2; ++kti)
        #pragma unroll
        for (int kc = 0; kc < 4; ++kc)
            koff[kti][kc] = ((((kh * 2 + kti) * 16 + c) * 128) + (((kc * 4 + quad) ^ c) * 8)) * 2;
    int voff[8][2];                    // GLOBAL V fragment offsets within a tile
    #pragma unroll
    for (int fi = 0; fi < 8; ++fi)
        #pragma unroll
        for (int kti = 0; kti < 2; ++kti) {
            int g = kh * 8 + kti * 4 + quad;
            voff[fi][kti] = g * 1024 + (fi * 16 + c) * 8;
        }

    // wave's Q m-tile as B-fragments (scaled by g, bf16), loop-invariant
    bf16x8 qfrag[4];
    {
        const float* qrow = XQ + (size_t)(b * L_ + q0 + msel * 16 + c) * D_;
        #pragma unroll
        for (int kc = 0; kc < 4; ++kc) {
            int d0 = kc * 32 + quad * 8;
            float4 v0 = *(const float4*)(qrow + d0);
            float4 v1 = *(const float4*)(qrow + d0 + 4);
            float4 g0 = *(const float4*)(g_s + d0);
            float4 g1 = *(const float4*)(g_s + d0 + 4);
            bf16x8 w;
            w[0] = (bf16)(v0.x * g0.x); w[1] = (bf16)(v0.y * g0.y);
            w[2] = (bf16)(v0.z * g0.z); w[3] = (bf16)(v0.w * g0.w);
            w[4] = (bf16)(v1.x * g1.x); w[5] = (bf16)(v1.y * g1.y);
            w[6] = (bf16)(v1.z * g1.z); w[7] = (bf16)(v1.w * g1.w);
            qfrag[kc] = w;
        }
    }

    f32x4 oacc[8];                     // partial O[m-tile msel][128 f] for kh's 32 k
    #pragma unroll
    for (int fi = 0; fi < 8; ++fi)
        #pragma unroll
        for (int r = 0; r < 4; ++r) oacc[fi][r] = 0.f;
    float lsum = 0.f;                  // per-lane: row m = msel*16+c, wave's k slice

    #pragma unroll 2
    for (int kt = 0; kt < NKT; ++kt) {
        const char* sK  = (kt & 1) ? (char*)sK1 : (char*)sK0;
        bf16* sKn = (kt & 1) ? sK0 : sK1;
        const char* gVt = gVbase + (size_t)kt * 16384;

        // A: all waves done reading buf[next]
        asm volatile("s_barrier" ::: "memory");

        u64 mb = mbc;

        if (kt + 1 < NKT) {
            const char* gk = gKbase + (size_t)(kt + 1) * 16384;
            #pragma unroll
            for (int i = 0; i < 2; ++i) dma16(gk + i * 8192 + tid * 16, (char*)sKn + i * 8192 + tid * 16);
            mbc = mrow[kt + 1];        // prefetch next tile's mask word
            // newest 3 = 1 mask + 2 next-DMA; prior-tile ops provably drained
            // (vmcnt retires in order; last iter's V loads were consumed)
            asm volatile("s_waitcnt vmcnt(3)" ::: "memory");
        } else {
            asm volatile("s_waitcnt vmcnt(0)" ::: "memory");
        }
        // B: tile kt resident
        asm volatile("s_barrier" ::: "memory");

        __builtin_amdgcn_s_setprio(1);

        // S^T = K @ Qg^T for wave's 2 k-tiles (kh*2+kti)
        f32x4 tacc[2];
        #pragma unroll
        for (int kti = 0; kti < 2; ++kti)
            #pragma unroll
            for (int r = 0; r < 4; ++r) tacc[kti][r] = 0.f;

        #pragma unroll
        for (int kti = 0; kti < 2; ++kti) {
            #pragma unroll
            for (int kc = 0; kc < 4; ++kc) {
                bf16x8 kfrag = *(const bf16x8*)(sK + koff[kti][kc]);
                tacc[kti] = mfma32(kfrag, qfrag[kc], tacc[kti]);
            }
        }

        // lane(c,quad) reg r = S^T[k = kh*32+kti*16+quad*4+r][m = msel*16+c]
        // -> exp2 (log2e folded) -> DIRECTLY the A-operand of 16x16x16 MFMA
        bf16x4 pfrag[2];
        #pragma unroll
        for (int kti = 0; kti < 2; ++kti) {
            #pragma unroll
            for (int r = 0; r < 4; ++r) {
                float p = ((mb >> (kh * 32 + kti * 16 + quad * 4 + r)) & 1ull)
                          ? fexp2(tacc[kti][r]) : 0.f;
                lsum += p;
                pfrag[kti][r] = (bf16)p;
            }
        }

        // O_partial += P @ V over wave's 32 k; V fragments straight from L2
        // (coalesced: lanes c=0..15 read consecutive 8B; 4x128B per instr)
        #pragma unroll
        for (int fi = 0; fi < 8; ++fi) {
            #pragma unroll
            for (int kti = 0; kti < 2; ++kti) {
                bf16x4 vfrag = *(const bf16x4*)(gVt + voff[fi][kti]);
                oacc[fi] = mfma16(pfrag[kti], vfrag, oacc[fi]);
            }
        }

        __builtin_amdgcn_s_setprio(0);
    }

    // publish per-wave row sums: lane c holds sum over wave's 32k after quad-reduce
    {
        float v = lsum;
        v += __shfl_xor(v, 16); v += __shfl_xor(v, 32);
        if (lane < 16) lws[wave * 16 + lane] = v;
    }
    if (tid < 128)
        g_s[tid] = WV[(h * F_ + tid) * F_ + tid];   // dv (g_s no longer needed)
    __syncthreads();   // main-loop LDS reads done; lws visible

    // normalizers for combiner waves (kh==0)
    float linv[4];
    if (kh == 0) {
        #pragma unroll
        for (int r = 0; r < 4; ++r) {
            int m16 = quad * 4 + r;
            linv[r] = 1.0f / (lws[msel * 16 + m16] + lws[(4 + msel) * 16 + m16]);
        }
    }

    // 2-way combine in two f-half rounds (pOx is only [64][68] f32)
    #pragma unroll
    for (int r2 = 0; r2 < 2; ++r2) {
        if (kh == 1) {
            #pragma unroll
            for (int fl = 0; fl < 4; ++fl)
                #pragma unroll
                for (int r = 0; r < 4; ++r)
                    pOx[(msel * 16 + quad * 4 + r) * POX_STRIDE + fl * 16 + c] = oacc[r2 * 4 + fl][r];
        }
        __syncthreads();
        if (kh == 0) {
            #pragma unroll
            for (int fl = 0; fl < 4; ++fl)
                #pragma unroll
                for (int r = 0; r < 4; ++r) {
                    int row = msel * 16 + quad * 4 + r;
                    float v = (oacc[r2 * 4 + fl][r] + pOx[row * POX_STRIDE + fl * 16 + c]) * linv[r];
                    sOh[row * SOH_STRIDE + (r2 * 4 + fl) * 16 + c] = (bf16)v;
                }
        }
        __syncthreads();
    }

    // stage O2^T: sO2t[f][f'] = O[h*128+f'][f] * dv[f']  (pOx region now dead)
    #pragma unroll
    for (int i = 0; i < 8; ++i) {
        int fp4 = grp * 32 + i * 4;
        bf16x4 w;
        #pragma unroll
        for (int j = 0; j < 4; ++j) {
            int x = fp4 + j;
            w[j] = (bf16)(Om[(h * F_ + x) * F_ + fv] * g_s[x]);
        }
        *(bf16x4*)(sO2t + fv * SO2_STRIDE + fp4) = w;
    }
    __syncthreads();

    // out_partial = Oh @ O2 : wave (pm = m-tile, pf = f-half)
    const int pm = wave & 3;
    const int pf = wave >> 2;
    bf16x8 afr[4];
    const bf16* ohrow = sOh + (pm * 16 + c) * SOH_STRIDE;
    #pragma unroll
    for (int kc = 0; kc < 4; ++kc)
        afr[kc] = *(const bf16x8*)(ohrow + kc * 32 + quad * 8);

    #pragma unroll
    for (int nt = 0; nt < 4; ++nt) {
        f32x4 pacc;
        #pragma unroll
        for (int r = 0; r < 4; ++r) pacc[r] = 0.f;
        const bf16* orow = sO2t + ((pf * 4 + nt) * 16 + c) * SO2_STRIDE;
        #pragma unroll
        for (int kc = 0; kc < 4; ++kc) {
            bf16x8 bfrag = *(const bf16x8*)(orow + kc * 32 + quad * 8);
            pacc = mfma32(afr[kc], bfrag, pacc);
        }
        #pragma unroll
        for (int r = 0; r < 4; ++r) {
            int qg = q0 + pm * 16 + quad * 4 + r;
            atomicAdd(out + ((size_t)(b * L_ + qg) * F_ + (pf * 4 + nt) * 16 + c), pacc[r]);
        }
    }
}

extern "C" void kernel_launch(void* const* d_in, const int* in_sizes, int n_in,
                              void* d_out, int out_size, void* d_ws, size_t ws_size,
                              hipStream_t stream) {
    const float* XQ   = (const float*)d_in[0];
    const float* XK   = (const float*)d_in[1];
    const float* XV   = (const float*)d_in[2];
    const int*   mask = (const int*)d_in[3];
    const float* WQ   = (const float*)d_in[4];
    const float* WK   = (const float*)d_in[5];
    const float* WV   = (const float*)d_in[6];
    const float* Om   = (const float*)d_in[7];
    float* out = (float*)d_out;

    char* ws = (char*)d_ws;
    bf16* Kb   = (bf16*)(ws + WS_KB);
    bf16* Vtb  = (bf16*)(ws + WS_VT);
    u64*  bits = (u64*)(ws + WS_MB);

    prep_one<<<2688, 256, 0, stream>>>(XK, XV, mask, Kb, Vtb, bits, out);

    dim3 grid(L_ / QT, H_, B_);
    attn_fused_kernel<<<grid, 512, 0, stream>>>(XQ, Kb, Vtb, bits, WQ, WK, WV, Om, out);
}

// Round 13
// 155.372 us; speedup vs baseline: 2.7876x; 1.4177x over previous
//
#include <hip/hip_runtime.h>

typedef __bf16 bf16;
typedef __bf16 bf16x4 __attribute__((ext_vector_type(4)));
typedef __bf16 bf16x8 __attribute__((ext_vector_type(8)));
typedef float f32x4 __attribute__((ext_vector_type(4)));
typedef short s16x4 __attribute__((ext_vector_type(4)));
typedef unsigned int u32;
typedef unsigned long long u64;

#define B_ 2
#define H_ 8
#define L_ 2048
#define D_ 128
#define F_ 128
#define QT 64
#define KT 64
#define NKT (L_ / KT)

// workspace layout (bytes)
#define WS_KB 0u            // Kb  : bf16 [b][k][16B-chunk swizzled], 1 MB
#define WS_VT (1u << 20)    // Vtb : bf16 tiles [b][kt][f][8B-group swz], 1 MB
#define WS_MB (2u << 20)    // bits: u64 [b][q][kt], 1 MB

// LDS main: sK0@0 sK1@16384 sV0@32768 sV1@49152 (16KB each), lws@65536 (512B)
// epilogue: pOx@0 f32 [64][132] = 33792 ; sOh@36864 bf16 [64][136] = 17408 ;
//           sO2t@0 bf16 [128][136] = 34816 (after pOx reads done) ; lws kept.
#define SMEM_BYTES 66048
#define LWS_OFF 65536
#define POX_STRIDE 132
#define SOH_OFF 36864
#define SOH_STRIDE 136
#define SO2_STRIDE 136

__device__ __forceinline__ void dma16(const void* g, void* l) {
    __builtin_amdgcn_global_load_lds(
        (const __attribute__((address_space(1))) u32*)g,
        (__attribute__((address_space(3))) u32*)l, 16, 0, 0);
}

__device__ __forceinline__ f32x4 mfma32(bf16x8 a, bf16x8 b, f32x4 c) {
    return __builtin_amdgcn_mfma_f32_16x16x32_bf16(a, b, c, 0, 0, 0);
}

__device__ __forceinline__ f32x4 mfma16(bf16x4 a, bf16x4 b, f32x4 c) {
#if __has_builtin(__builtin_amdgcn_mfma_f32_16x16x16_bf16)
    return __builtin_amdgcn_mfma_f32_16x16x16_bf16(a, b, c, 0, 0, 0);
#else
    s16x4 as = __builtin_bit_cast(s16x4, a);
    s16x4 bs = __builtin_bit_cast(s16x4, b);
    return __builtin_amdgcn_mfma_f32_16x16x16bf16_1k(as, bs, c, 0, 0, 0);
#endif
}

// guaranteed single-instruction exp2 (log2e is folded into g_s upstream)
__device__ __forceinline__ float fexp2(float x) {
#if __has_builtin(__builtin_amdgcn_exp2f)
    return __builtin_amdgcn_exp2f(x);
#else
    float r;
    asm("v_exp_f32 %0, %1" : "=v"(r) : "v"(x));
    return r;
#endif
}

// spread 16 bits to stride-4 positions of a u64 (bit i -> bit 4i)
__device__ __forceinline__ u64 spread4(u64 v) {
    v = (v | (v << 24)) & 0x000000ff000000ffULL;
    v = (v | (v << 12)) & 0x000f000f000f000fULL;
    v = (v | (v << 6))  & 0x0303030303030303ULL;
    v = (v | (v << 3))  & 0x1111111111111111ULL;
    return v;
}

// ---- SINGLE prep launch: mask bitpack (0..2047), K cvt+swz (2048..2303),
//      V^T tiles (2304..2559), out zero (2560..2687).
// R9 falsified direct mask reads in attn (uncoalesced, 69.6->83.4us);
// R12 falsified V-from-L2 (latency-bound PV, 69.5->135us). Bitpack + LDS-V stay.
__global__ __launch_bounds__(256)
void prep_one(const float* __restrict__ XK, const float* __restrict__ XV,
              const int* __restrict__ mask, bf16* __restrict__ Kb,
              bf16* __restrict__ Vtb, u64* __restrict__ bits,
              float* __restrict__ out)
{
    const int bid = blockIdx.x;
    const int tid = threadIdx.x;
    if (bid < 2048) {
        // mask bitpack: wave-iter W handles 256 ints (16B/lane); 4 ballots +
        // stride-4 spread on lanes 0..3 rebuild bits[W*4+q] (R8-verified).
        const int lane = tid & 63;
        const int wv   = bid * 4 + (tid >> 6);     // 0..8191
        const int4* m4 = (const int4*)mask;
        #pragma unroll
        for (int t = 0; t < 4; ++t) {
            int W = wv + t * 8192;                 // 0..32767
            int4 v = m4[(size_t)W * 64 + lane];
            int nib = (v.x != 0 ? 1 : 0) | (v.y != 0 ? 2 : 0)
                    | (v.z != 0 ? 4 : 0) | (v.w != 0 ? 8 : 0);
            u64 b0 = __ballot(nib & 1);
            u64 b1 = __ballot(nib & 2);
            u64 b2 = __ballot(nib & 4);
            u64 b3 = __ballot(nib & 8);
            if (lane < 4) {
                int sh = lane * 16;
                u64 w = spread4((b0 >> sh) & 0xFFFFull)
                      | (spread4((b1 >> sh) & 0xFFFFull) << 1)
                      | (spread4((b2 >> sh) & 0xFFFFull) << 2)
                      | (spread4((b3 >> sh) & 0xFFFFull) << 3);
                bits[(size_t)W * 4 + lane] = w;
            }
        }
    } else if (bid < 2304) {
        int gid = (bid - 2048) * 256 + tid;
        int row = gid >> 4;
        int j   = gid & 15;
        const float* src = XK + (size_t)row * 128 + j * 8;
        float4 v0 = *(const float4*)src;
        float4 v1 = *(const float4*)(src + 4);
        bf16x8 w;
        w[0] = (bf16)v0.x; w[1] = (bf16)v0.y; w[2] = (bf16)v0.z; w[3] = (bf16)v0.w;
        w[4] = (bf16)v1.x; w[5] = (bf16)v1.y; w[6] = (bf16)v1.z; w[7] = (bf16)v1.w;
        int jp = j ^ (row & 15);
        *(bf16x8*)(Kb + (size_t)row * 128 + jp * 8) = w;
    } else if (bid < 2560) {
        // V^T tiles [tile][f][64k]; 8B group g (k=4g..4g+3) stored at g^(f&15)
        int idx  = bid - 2304;
        int tile = idx >> 2;
        int fq   = idx & 3;
        int f    = fq * 32 + (tid & 31);
        int j    = tid >> 5;                  // 0..7 -> k = 8j..8j+7
        int bb   = tile >> 5, kt = tile & 31;
        const float* src = XV + ((size_t)(bb * L_ + kt * 64 + j * 8)) * F_ + f;
        bf16x4 w0, w1;
        #pragma unroll
        for (int jj = 0; jj < 4; ++jj) {
            w0[jj] = (bf16)src[(size_t)jj * F_];
            w1[jj] = (bf16)src[(size_t)(4 + jj) * F_];
        }
        bf16* outp = Vtb + (size_t)tile * 8192 + f * 64;
        *(bf16x4*)(outp + (((2 * j) ^ (f & 15)) * 4)) = w0;
        *(bf16x4*)(outp + (((2 * j + 1) ^ (f & 15)) * 4)) = w1;
    } else {
        // zero out[] (B*L*F floats = 131072 float4), replaces hipMemsetAsync
        float4* o4 = (float4*)out;
        int idx = (bid - 2560) * 256 + tid;        // 0..32767
        float4 z; z.x = 0.f; z.y = 0.f; z.z = 0.f; z.w = 0.f;
        #pragma unroll
        for (int t = 0; t < 4; ++t) o4[idx + t * 32768] = z;
    }
}

// ---- main fused kernel: 512 threads / 8 waves; wave = (kh, msel) ----
// MEASURED-BEST configuration (R10: attn 69.5us, total 152.0us).
// Geometry: 512 blocks, 2 blocks/CU (LDS-capped), 16 waves/CU.
// REGISTER-CAP RULE (R3/R4/R11): no launch_bounds 2nd arg, no waves_per_eu>4;
// (4,4) is the only safe attribute (VGPR 64, no spill).
// Falsified alternatives: QT=128 (R1, 87us), 2-m-tiles/wave (R4, 114us),
// direct mask (R9, 83us), V-from-L2 (R12, 135us).
__global__ __launch_bounds__(512)
__attribute__((amdgpu_waves_per_eu(4, 4)))
void attn_fused_kernel(const float* __restrict__ XQ, const bf16* __restrict__ Kb,
                       const bf16* __restrict__ Vtb, const u64* __restrict__ bits,
                       const float* __restrict__ WQ, const float* __restrict__ WK,
                       const float* __restrict__ WV, const float* __restrict__ Om,
                       float* __restrict__ out)
{
    __shared__ __align__(16) char smem[SMEM_BYTES];
    __shared__ __align__(16) float g_s[128];

    bf16* sK0 = (bf16*)smem;
    bf16* sK1 = (bf16*)(smem + 16384);
    bf16* sV0 = (bf16*)(smem + 32768);
    bf16* sV1 = (bf16*)(smem + 49152);
    float* lws = (float*)(smem + LWS_OFF);
    float* pOx = (float*)smem;                 // epilogue
    bf16* sOh  = (bf16*)(smem + SOH_OFF);      // epilogue
    bf16* sO2t = (bf16*)smem;                  // epilogue (after pOx reads done)

    const int tid  = threadIdx.x;
    const int wave = tid >> 6;        // 0..7
    const int lane = tid & 63;
    const int c    = lane & 15;
    const int quad = lane >> 4;
    const int qt = blockIdx.x, h = blockIdx.y, b = blockIdx.z;
    const int q0 = qt * QT;

    const int kh   = wave >> 2;       // k-half (32 k)
    const int msel = wave & 3;        // m-tile (16 m)
    const int fv  = tid & 127;        // epilogue staging
    const int grp = tid >> 7;         // 0..3

    if (tid < 128) {
        float wq = WQ[(h * D_ + tid) * D_ + tid];
        float wk = WK[(h * D_ + tid) * D_ + tid];
        // fold softmax scale AND log2(e): exp becomes a raw v_exp_f32
        g_s[tid] = wq * wk * 0.08838834764831845f * 1.4426950408889634f;
    }
    __syncthreads();

    const char* gKbase = (const char*)Kb + (size_t)(b * L_) * 256;
    const char* gVbase = (const char*)Vtb + (size_t)(b * NKT) * 16384;

    // DMA tile 0
    #pragma unroll
    for (int i = 0; i < 2; ++i) dma16(gKbase + i * 8192 + tid * 16, (char*)sK0 + i * 8192 + tid * 16);
    #pragma unroll
    for (int i = 0; i < 2; ++i) dma16(gVbase + i * 8192 + tid * 16, (char*)sV0 + i * 8192 + tid * 16);

    const u64* mrow = bits + (size_t)(b * L_ + q0 + msel * 16 + c) * NKT;
    u64 mbc = mrow[0];                 // mask prefetch (one k-tile ahead)

    // hoisted loop-invariant LDS byte offsets (statically indexed -> registers)
    int koff[2][4];
    #pragma unroll
    for (int kti = 0; kti < 2; ++kti)
        #pragma unroll
        for (int kc = 0; kc < 4; ++kc)
            koff[kti][kc] = ((((kh * 2 + kti) * 16 + c) * 128) + (((kc * 4 + quad) ^ c) * 8)) * 2;
    int voff[8][2];
    #pragma unroll
    for (int fi = 0; fi < 8; ++fi)
        #pragma unroll
        for (int kti = 0; kti < 2; ++kti) {
            int g = kh * 8 + kti * 4 + quad;
            voff[fi][kti] = (((fi * 16 + c) * 64) + ((g ^ c) * 4)) * 2;
        }

    // wave's Q m-tile as B-fragments (scaled by g, bf16), loop-invariant
    bf16x8 qfrag[4];
    {
        const float* qrow = XQ + (size_t)(b * L_ + q0 + msel * 16 + c) * D_;
        #pragma unroll
        for (int kc = 0; kc < 4; ++kc) {
            int d0 = kc * 32 + quad * 8;
            float4 v0 = *(const float4*)(qrow + d0);
            float4 v1 = *(const float4*)(qrow + d0 + 4);
            float4 g0 = *(const float4*)(g_s + d0);
            float4 g1 = *(const float4*)(g_s + d0 + 4);
            bf16x8 w;
            w[0] = (bf16)(v0.x * g0.x); w[1] = (bf16)(v0.y * g0.y);
            w[2] = (bf16)(v0.z * g0.z); w[3] = (bf16)(v0.w * g0.w);
            w[4] = (bf16)(v1.x * g1.x); w[5] = (bf16)(v1.y * g1.y);
            w[6] = (bf16)(v1.z * g1.z); w[7] = (bf16)(v1.w * g1.w);
            qfrag[kc] = w;
        }
    }

    f32x4 oacc[8];                     // partial O[m-tile msel][128 f] for kh's 32 k
    #pragma unroll
    for (int fi = 0; fi < 8; ++fi)
        #pragma unroll
        for (int r = 0; r < 4; ++r) oacc[fi][r] = 0.f;
    float lsum = 0.f;                  // per-lane: row m = msel*16+c, wave's k slice

    #pragma unroll 2
    for (int kt = 0; kt < NKT; ++kt) {
        const char* sK  = (kt & 1) ? (char*)sK1 : (char*)sK0;
        const char* sV  = (kt & 1) ? (char*)sV1 : (char*)sV0;
        bf16* sKn = (kt & 1) ? sK0 : sK1;
        bf16* sVn = (kt & 1) ? sV0 : sV1;

        // A: all waves done reading buf[next]
        asm volatile("s_barrier" ::: "memory");

        u64 mb = mbc;

        if (kt + 1 < NKT) {
            const char* gk = gKbase + (size_t)(kt + 1) * 16384;
            const char* gv = gVbase + (size_t)(kt + 1) * 16384;
            #pragma unroll
            for (int i = 0; i < 2; ++i) dma16(gk + i * 8192 + tid * 16, (char*)sKn + i * 8192 + tid * 16);
            #pragma unroll
            for (int i = 0; i < 2; ++i) dma16(gv + i * 8192 + tid * 16, (char*)sVn + i * 8192 + tid * 16);
            mbc = mrow[kt + 1];        // prefetch next tile's mask word
            // newest 5 = 1 mask + 4 next-DMA -> tile kt's DMA drained
            asm volatile("s_waitcnt vmcnt(5)" ::: "memory");
        } else {
            asm volatile("s_waitcnt vmcnt(0)" ::: "memory");
        }
        // B: tile kt resident
        asm volatile("s_barrier" ::: "memory");

        __builtin_amdgcn_s_setprio(1);

        // S^T = K @ Qg^T for wave's 2 k-tiles (kh*2+kti)
        f32x4 tacc[2];
        #pragma unroll
        for (int kti = 0; kti < 2; ++kti)
            #pragma unroll
            for (int r = 0; r < 4; ++r) tacc[kti][r] = 0.f;

        #pragma unroll
        for (int kti = 0; kti < 2; ++kti) {
            #pragma unroll
            for (int kc = 0; kc < 4; ++kc) {
                bf16x8 kfrag = *(const bf16x8*)(sK + koff[kti][kc]);
                tacc[kti] = mfma32(kfrag, qfrag[kc], tacc[kti]);
            }
        }

        // lane(c,quad) reg r = S^T[k = kh*32+kti*16+quad*4+r][m = msel*16+c]
        // -> exp2 (log2e folded) -> DIRECTLY the A-operand of 16x16x16 MFMA
        bf16x4 pfrag[2];
        #pragma unroll
        for (int kti = 0; kti < 2; ++kti) {
            #pragma unroll
            for (int r = 0; r < 4; ++r) {
                float p = ((mb >> (kh * 32 + kti * 16 + quad * 4 + r)) & 1ull)
                          ? fexp2(tacc[kti][r]) : 0.f;
                lsum += p;
                pfrag[kti][r] = (bf16)p;
            }
        }

        // O_partial += P @ V over wave's 32 k (no LDS round trip, no 3rd barrier)
        #pragma unroll
        for (int fi = 0; fi < 8; ++fi) {
            #pragma unroll
            for (int kti = 0; kti < 2; ++kti) {
                bf16x4 vfrag = *(const bf16x4*)(sV + voff[fi][kti]);
                oacc[fi] = mfma16(pfrag[kti], vfrag, oacc[fi]);
            }
        }

        __builtin_amdgcn_s_setprio(0);
    }

    // publish per-wave row sums: lane c holds sum over wave's 32k after quad-reduce
    {
        float v = lsum;
        v += __shfl_xor(v, 16); v += __shfl_xor(v, 32);
        if (lane < 16) lws[wave * 16 + lane] = v;
    }
    if (tid < 128)
        g_s[tid] = WV[(h * F_ + tid) * F_ + tid];   // dv (g_s no longer needed)
    __syncthreads();   // main-loop LDS reads done; lws visible

    // kh=1 waves dump partial O to pOx
    if (kh == 1) {
        #pragma unroll
        for (int fi = 0; fi < 8; ++fi)
            #pragma unroll
            for (int r = 0; r < 4; ++r)
                pOx[(msel * 16 + quad * 4 + r) * POX_STRIDE + fi * 16 + c] = oacc[fi][r];
    }
    __syncthreads();

    // kh=0 waves: combine halves, normalize, write sOh (bf16)
    if (kh == 0) {
        float linv[4];
        #pragma unroll
        for (int r = 0; r < 4; ++r) {
            int m16 = quad * 4 + r;
            linv[r] = 1.0f / (lws[msel * 16 + m16] + lws[(4 + msel) * 16 + m16]);
        }
        #pragma unroll
        for (int fi = 0; fi < 8; ++fi)
            #pragma unroll
            for (int r = 0; r < 4; ++r) {
                int row = msel * 16 + quad * 4 + r;
                float v = (oacc[fi][r] + pOx[row * POX_STRIDE + fi * 16 + c]) * linv[r];
                sOh[row * SOH_STRIDE + fi * 16 + c] = (bf16)v;
            }
    }
    __syncthreads();

    // stage O2^T: sO2t[f][f'] = O[h*128+f'][f] * dv[f']  (reuses pOx region)
    #pragma unroll
    for (int i = 0; i < 8; ++i) {
        int fp4 = grp * 32 + i * 4;
        bf16x4 w;
        #pragma unroll
        for (int j = 0; j < 4; ++j) {
            int x = fp4 + j;
            w[j] = (bf16)(Om[(h * F_ + x) * F_ + fv] * g_s[x]);
        }
        *(bf16x4*)(sO2t + fv * SO2_STRIDE + fp4) = w;
    }
    __syncthreads();

    // out_partial = Oh @ O2 : wave (pm = m-tile, pf = f-half)
    const int pm = wave & 3;
    const int pf = wave >> 2;
    bf16x8 afr[4];
    const bf16* ohrow = sOh + (pm * 16 + c) * SOH_STRIDE;
    #pragma unroll
    for (int kc = 0; kc < 4; ++kc)
        afr[kc] = *(const bf16x8*)(ohrow + kc * 32 + quad * 8);

    #pragma unroll
    for (int nt = 0; nt < 4; ++nt) {
        f32x4 pacc;
        #pragma unroll
        for (int r = 0; r < 4; ++r) pacc[r] = 0.f;
        const bf16* orow = sO2t + ((pf * 4 + nt) * 16 + c) * SO2_STRIDE;
        #pragma unroll
        for (int kc = 0; kc < 4; ++kc) {
            bf16x8 bfrag = *(const bf16x8*)(orow + kc * 32 + quad * 8);
            pacc = mfma32(afr[kc], bfrag, pacc);
        }
        #pragma unroll
        for (int r = 0; r < 4; ++r) {
            int qg = q0 + pm * 16 + quad * 4 + r;
            atomicAdd(out + ((size_t)(b * L_ + qg) * F_ + (pf * 4 + nt) * 16 + c), pacc[r]);
        }
    }
}

extern "C" void kernel_launch(void* const* d_in, const int* in_sizes, int n_in,
                              void* d_out, int out_size, void* d_ws, size_t ws_size,
                              hipStream_t stream) {
    const float* XQ   = (const float*)d_in[0];
    const float* XK   = (const float*)d_in[1];
    const float* XV   = (const float*)d_in[2];
    const int*   mask = (const int*)d_in[3];
    const float* WQ   = (const float*)d_in[4];
    const float* WK   = (const float*)d_in[5];
    const float* WV   = (const float*)d_in[6];
    const float* Om   = (const float*)d_in[7];
    float* out = (float*)d_out;

    char* ws = (char*)d_ws;
    bf16* Kb   = (bf16*)(ws + WS_KB);
    bf16* Vtb  = (bf16*)(ws + WS_VT);
    u64*  bits = (u64*)(ws + WS_MB);

    prep_one<<<2688, 256, 0, stream>>>(XK, XV, mask, Kb, Vtb, bits, out);

    dim3 grid(L_ / QT, H_, B_);
    attn_fused_kernel<<<grid, 512, 0, stream>>>(XQ, Kb, Vtb, bits, WQ, WK, WV, Om, out);
}

// Round 14
// 154.153 us; speedup vs baseline: 2.8097x; 1.0079x over previous
//
#include <hip/hip_runtime.h>

typedef __bf16 bf16;
typedef __bf16 bf16x4 __attribute__((ext_vector_type(4)));
typedef __bf16 bf16x8 __attribute__((ext_vector_type(8)));
typedef float f32x4 __attribute__((ext_vector_type(4)));
typedef short s16x4 __attribute__((ext_vector_type(4)));
typedef unsigned int u32;
typedef unsigned long long u64;

#define B_ 2
#define H_ 8
#define L_ 2048
#define D_ 128
#define F_ 128
#define QT 64
#define KT 64
#define NKT (L_ / KT)

// workspace layout (bytes)
#define WS_KB 0u            // Kb  : bf16 [b][k][16B-chunk swizzled], 1 MB
#define WS_VT (1u << 20)    // Vtb : bf16 tiles [b][kt][f][8B-group swz], 1 MB
#define WS_MB (2u << 20)    // bits: u64 [b][q][kt], 1 MB

// LDS main: sK0@0 sK1@16384 sV0@32768 sV1@49152 (16KB each), lws@65536 (512B)
// epilogue: pOx@0 f32 [64][132] = 33792 ; sOh@36864 bf16 [64][136] = 17408 ;
//           sO2t@0 bf16 [128][136] = 34816 (after pOx reads done) ; lws kept.
#define SMEM_BYTES 66048
#define LWS_OFF 65536
#define POX_STRIDE 132
#define SOH_OFF 36864
#define SOH_STRIDE 136
#define SO2_STRIDE 136

__device__ __forceinline__ void dma16(const void* g, void* l) {
    __builtin_amdgcn_global_load_lds(
        (const __attribute__((address_space(1))) u32*)g,
        (__attribute__((address_space(3))) u32*)l, 16, 0, 0);
}

__device__ __forceinline__ f32x4 mfma32(bf16x8 a, bf16x8 b, f32x4 c) {
    return __builtin_amdgcn_mfma_f32_16x16x32_bf16(a, b, c, 0, 0, 0);
}

__device__ __forceinline__ f32x4 mfma16(bf16x4 a, bf16x4 b, f32x4 c) {
#if __has_builtin(__builtin_amdgcn_mfma_f32_16x16x16_bf16)
    return __builtin_amdgcn_mfma_f32_16x16x16_bf16(a, b, c, 0, 0, 0);
#else
    s16x4 as = __builtin_bit_cast(s16x4, a);
    s16x4 bs = __builtin_bit_cast(s16x4, b);
    return __builtin_amdgcn_mfma_f32_16x16x16bf16_1k(as, bs, c, 0, 0, 0);
#endif
}

// guaranteed single-instruction exp2 (log2e is folded into g_s upstream)
__device__ __forceinline__ float fexp2(float x) {
#if __has_builtin(__builtin_amdgcn_exp2f)
    return __builtin_amdgcn_exp2f(x);
#else
    float r;
    asm("v_exp_f32 %0, %1" : "=v"(r) : "v"(x));
    return r;
#endif
}

// spread 16 bits to stride-4 positions of a u64 (bit i -> bit 4i)
__device__ __forceinline__ u64 spread4(u64 v) {
    v = (v | (v << 24)) & 0x000000ff000000ffULL;
    v = (v | (v << 12)) & 0x000f000f000f000fULL;
    v = (v | (v << 6))  & 0x0303030303030303ULL;
    v = (v | (v << 3))  & 0x1111111111111111ULL;
    return v;
}

// ---- SINGLE prep launch: mask bitpack (0..2047), K cvt+swz (2048..2303),
//      V^T tiles (2304..2559), out zero (2560..2687).
// R9 falsified direct mask reads in attn (uncoalesced, 69.6->83.4us);
// R12 falsified V-from-L2 (latency-bound PV, 69.5->135us). Bitpack + LDS-V stay.
__global__ __launch_bounds__(256)
void prep_one(const float* __restrict__ XK, const float* __restrict__ XV,
              const int* __restrict__ mask, bf16* __restrict__ Kb,
              bf16* __restrict__ Vtb, u64* __restrict__ bits,
              float* __restrict__ out)
{
    const int bid = blockIdx.x;
    const int tid = threadIdx.x;
    if (bid < 2048) {
        // mask bitpack: wave-iter W handles 256 ints (16B/lane); 4 ballots +
        // stride-4 spread on lanes 0..3 rebuild bits[W*4+q] (R8-verified).
        const int lane = tid & 63;
        const int wv   = bid * 4 + (tid >> 6);     // 0..8191
        const int4* m4 = (const int4*)mask;
        #pragma unroll
        for (int t = 0; t < 4; ++t) {
            int W = wv + t * 8192;                 // 0..32767
            int4 v = m4[(size_t)W * 64 + lane];
            int nib = (v.x != 0 ? 1 : 0) | (v.y != 0 ? 2 : 0)
                    | (v.z != 0 ? 4 : 0) | (v.w != 0 ? 8 : 0);
            u64 b0 = __ballot(nib & 1);
            u64 b1 = __ballot(nib & 2);
            u64 b2 = __ballot(nib & 4);
            u64 b3 = __ballot(nib & 8);
            if (lane < 4) {
                int sh = lane * 16;
                u64 w = spread4((b0 >> sh) & 0xFFFFull)
                      | (spread4((b1 >> sh) & 0xFFFFull) << 1)
                      | (spread4((b2 >> sh) & 0xFFFFull) << 2)
                      | (spread4((b3 >> sh) & 0xFFFFull) << 3);
                bits[(size_t)W * 4 + lane] = w;
            }
        }
    } else if (bid < 2304) {
        int gid = (bid - 2048) * 256 + tid;
        int row = gid >> 4;
        int j   = gid & 15;
        const float* src = XK + (size_t)row * 128 + j * 8;
        float4 v0 = *(const float4*)src;
        float4 v1 = *(const float4*)(src + 4);
        bf16x8 w;
        w[0] = (bf16)v0.x; w[1] = (bf16)v0.y; w[2] = (bf16)v0.z; w[3] = (bf16)v0.w;
        w[4] = (bf16)v1.x; w[5] = (bf16)v1.y; w[6] = (bf16)v1.z; w[7] = (bf16)v1.w;
        int jp = j ^ (row & 15);
        *(bf16x8*)(Kb + (size_t)row * 128 + jp * 8) = w;
    } else if (bid < 2560) {
        // V^T tiles [tile][f][64k]; 8B group g (k=4g..4g+3) stored at g^(f&15)
        int idx  = bid - 2304;
        int tile = idx >> 2;
        int fq   = idx & 3;
        int f    = fq * 32 + (tid & 31);
        int j    = tid >> 5;                  // 0..7 -> k = 8j..8j+7
        int bb   = tile >> 5, kt = tile & 31;
        const float* src = XV + ((size_t)(bb * L_ + kt * 64 + j * 8)) * F_ + f;
        bf16x4 w0, w1;
        #pragma unroll
        for (int jj = 0; jj < 4; ++jj) {
            w0[jj] = (bf16)src[(size_t)jj * F_];
            w1[jj] = (bf16)src[(size_t)(4 + jj) * F_];
        }
        bf16* outp = Vtb + (size_t)tile * 8192 + f * 64;
        *(bf16x4*)(outp + (((2 * j) ^ (f & 15)) * 4)) = w0;
        *(bf16x4*)(outp + (((2 * j + 1) ^ (f & 15)) * 4)) = w1;
    } else {
        // zero out[] (B*L*F floats = 131072 float4), replaces hipMemsetAsync
        float4* o4 = (float4*)out;
        int idx = (bid - 2560) * 256 + tid;        // 0..32767
        float4 z; z.x = 0.f; z.y = 0.f; z.z = 0.f; z.w = 0.f;
        #pragma unroll
        for (int t = 0; t < 4; ++t) o4[idx + t * 32768] = z;
    }
}

// ---- main fused kernel: 512 threads / 8 waves; wave = (kh, msel) ----
// MEASURED-BEST configuration (R10/R13: attn 69.5us). Geometry: 512 blocks,
// 2 blocks/CU (LDS-capped), 16 waves/CU.
// REGISTER-CAP RULE (R3/R4/R11): no launch_bounds 2nd arg, no waves_per_eu>4;
// (4,4) is the only safe attribute (VGPR 64, no spill).
// Falsified alternatives: QT=128 (R1, 87us), 2-m-tiles/wave (R4, 114us),
// direct mask (R9, 83us), V-from-L2 (R12, 135us).
// R14: mask pre-shift -- one u64 shift/iter instead of eight; bit tests
// become 32-bit constant-mask ANDs (register-neutral VALU shave).
__global__ __launch_bounds__(512)
__attribute__((amdgpu_waves_per_eu(4, 4)))
void attn_fused_kernel(const float* __restrict__ XQ, const bf16* __restrict__ Kb,
                       const bf16* __restrict__ Vtb, const u64* __restrict__ bits,
                       const float* __restrict__ WQ, const float* __restrict__ WK,
                       const float* __restrict__ WV, const float* __restrict__ Om,
                       float* __restrict__ out)
{
    __shared__ __align__(16) char smem[SMEM_BYTES];
    __shared__ __align__(16) float g_s[128];

    bf16* sK0 = (bf16*)smem;
    bf16* sK1 = (bf16*)(smem + 16384);
    bf16* sV0 = (bf16*)(smem + 32768);
    bf16* sV1 = (bf16*)(smem + 49152);
    float* lws = (float*)(smem + LWS_OFF);
    float* pOx = (float*)smem;                 // epilogue
    bf16* sOh  = (bf16*)(smem + SOH_OFF);      // epilogue
    bf16* sO2t = (bf16*)smem;                  // epilogue (after pOx reads done)

    const int tid  = threadIdx.x;
    const int wave = tid >> 6;        // 0..7
    const int lane = tid & 63;
    const int c    = lane & 15;
    const int quad = lane >> 4;
    const int qt = blockIdx.x, h = blockIdx.y, b = blockIdx.z;
    const int q0 = qt * QT;

    const int kh   = wave >> 2;       // k-half (32 k)
    const int msel = wave & 3;        // m-tile (16 m)
    const int fv  = tid & 127;        // epilogue staging
    const int grp = tid >> 7;         // 0..3

    if (tid < 128) {
        float wq = WQ[(h * D_ + tid) * D_ + tid];
        float wk = WK[(h * D_ + tid) * D_ + tid];
        // fold softmax scale AND log2(e): exp becomes a raw v_exp_f32
        g_s[tid] = wq * wk * 0.08838834764831845f * 1.4426950408889634f;
    }
    __syncthreads();

    const char* gKbase = (const char*)Kb + (size_t)(b * L_) * 256;
    const char* gVbase = (const char*)Vtb + (size_t)(b * NKT) * 16384;

    // DMA tile 0
    #pragma unroll
    for (int i = 0; i < 2; ++i) dma16(gKbase + i * 8192 + tid * 16, (char*)sK0 + i * 8192 + tid * 16);
    #pragma unroll
    for (int i = 0; i < 2; ++i) dma16(gVbase + i * 8192 + tid * 16, (char*)sV0 + i * 8192 + tid * 16);

    const u64* mrow = bits + (size_t)(b * L_ + q0 + msel * 16 + c) * NKT;
    u64 mbc = mrow[0];                 // mask prefetch (one k-tile ahead)
    const int mshift = kh * 32 + quad * 4;   // wave-constant mask pre-shift

    // hoisted loop-invariant LDS byte offsets (statically indexed -> registers)
    int koff[2][4];
    #pragma unroll
    for (int kti = 0; kti < 2; ++kti)
        #pragma unroll
        for (int kc = 0; kc < 4; ++kc)
            koff[kti][kc] = ((((kh * 2 + kti) * 16 + c) * 128) + (((kc * 4 + quad) ^ c) * 8)) * 2;
    int voff[8][2];
    #pragma unroll
    for (int fi = 0; fi < 8; ++fi)
        #pragma unroll
        for (int kti = 0; kti < 2; ++kti) {
            int g = kh * 8 + kti * 4 + quad;
            voff[fi][kti] = (((fi * 16 + c) * 64) + ((g ^ c) * 4)) * 2;
        }

    // wave's Q m-tile as B-fragments (scaled by g, bf16), loop-invariant
    bf16x8 qfrag[4];
    {
        const float* qrow = XQ + (size_t)(b * L_ + q0 + msel * 16 + c) * D_;
        #pragma unroll
        for (int kc = 0; kc < 4; ++kc) {
            int d0 = kc * 32 + quad * 8;
            float4 v0 = *(const float4*)(qrow + d0);
            float4 v1 = *(const float4*)(qrow + d0 + 4);
            float4 g0 = *(const float4*)(g_s + d0);
            float4 g1 = *(const float4*)(g_s + d0 + 4);
            bf16x8 w;
            w[0] = (bf16)(v0.x * g0.x); w[1] = (bf16)(v0.y * g0.y);
            w[2] = (bf16)(v0.z * g0.z); w[3] = (bf16)(v0.w * g0.w);
            w[4] = (bf16)(v1.x * g1.x); w[5] = (bf16)(v1.y * g1.y);
            w[6] = (bf16)(v1.z * g1.z); w[7] = (bf16)(v1.w * g1.w);
            qfrag[kc] = w;
        }
    }

    f32x4 oacc[8];                     // partial O[m-tile msel][128 f] for kh's 32 k
    #pragma unroll
    for (int fi = 0; fi < 8; ++fi)
        #pragma unroll
        for (int r = 0; r < 4; ++r) oacc[fi][r] = 0.f;
    float lsum = 0.f;                  // per-lane: row m = msel*16+c, wave's k slice

    #pragma unroll 2
    for (int kt = 0; kt < NKT; ++kt) {
        const char* sK  = (kt & 1) ? (char*)sK1 : (char*)sK0;
        const char* sV  = (kt & 1) ? (char*)sV1 : (char*)sV0;
        bf16* sKn = (kt & 1) ? sK0 : sK1;
        bf16* sVn = (kt & 1) ? sV0 : sV1;

        // A: all waves done reading buf[next]
        asm volatile("s_barrier" ::: "memory");

        u64 mb = mbc;

        if (kt + 1 < NKT) {
            const char* gk = gKbase + (size_t)(kt + 1) * 16384;
            const char* gv = gVbase + (size_t)(kt + 1) * 16384;
            #pragma unroll
            for (int i = 0; i < 2; ++i) dma16(gk + i * 8192 + tid * 16, (char*)sKn + i * 8192 + tid * 16);
            #pragma unroll
            for (int i = 0; i < 2; ++i) dma16(gv + i * 8192 + tid * 16, (char*)sVn + i * 8192 + tid * 16);
            mbc = mrow[kt + 1];        // prefetch next tile's mask word
            // newest 5 = 1 mask + 4 next-DMA -> tile kt's DMA drained
            asm volatile("s_waitcnt vmcnt(5)" ::: "memory");
        } else {
            asm volatile("s_waitcnt vmcnt(0)" ::: "memory");
        }
        // B: tile kt resident
        asm volatile("s_barrier" ::: "memory");

        __builtin_amdgcn_s_setprio(1);

        // S^T = K @ Qg^T for wave's 2 k-tiles (kh*2+kti)
        f32x4 tacc[2];
        #pragma unroll
        for (int kti = 0; kti < 2; ++kti)
            #pragma unroll
            for (int r = 0; r < 4; ++r) tacc[kti][r] = 0.f;

        #pragma unroll
        for (int kti = 0; kti < 2; ++kti) {
            #pragma unroll
            for (int kc = 0; kc < 4; ++kc) {
                bf16x8 kfrag = *(const bf16x8*)(sK + koff[kti][kc]);
                tacc[kti] = mfma32(kfrag, qfrag[kc], tacc[kti]);
            }
        }

        // lane(c,quad) reg r = S^T[k = kh*32+kti*16+quad*4+r][m = msel*16+c]
        // mask: ONE u64 pre-shift, then 32-bit constant-mask tests
        // (lane's 8 bits sit at positions kti*16+r <= 19 of the shifted word)
        u32 mw = (u32)(mb >> mshift);
        bf16x4 pfrag[2];
        #pragma unroll
        for (int kti = 0; kti < 2; ++kti) {
            #pragma unroll
            for (int r = 0; r < 4; ++r) {
                float p = (mw & (1u << (kti * 16 + r)))
                          ? fexp2(tacc[kti][r]) : 0.f;
                lsum += p;
                pfrag[kti][r] = (bf16)p;
            }
        }

        // O_partial += P @ V over wave's 32 k (no LDS round trip, no 3rd barrier)
        #pragma unroll
        for (int fi = 0; fi < 8; ++fi) {
            #pragma unroll
            for (int kti = 0; kti < 2; ++kti) {
                bf16x4 vfrag = *(const bf16x4*)(sV + voff[fi][kti]);
                oacc[fi] = mfma16(pfrag[kti], vfrag, oacc[fi]);
            }
        }

        __builtin_amdgcn_s_setprio(0);
    }

    // publish per-wave row sums: lane c holds sum over wave's 32k after quad-reduce
    {
        float v = lsum;
        v += __shfl_xor(v, 16); v += __shfl_xor(v, 32);
        if (lane < 16) lws[wave * 16 + lane] = v;
    }
    if (tid < 128)
        g_s[tid] = WV[(h * F_ + tid) * F_ + tid];   // dv (g_s no longer needed)
    __syncthreads();   // main-loop LDS reads done; lws visible

    // kh=1 waves dump partial O to pOx
    if (kh == 1) {
        #pragma unroll
        for (int fi = 0; fi < 8; ++fi)
            #pragma unroll
            for (int r = 0; r < 4; ++r)
                pOx[(msel * 16 + quad * 4 + r) * POX_STRIDE + fi * 16 + c] = oacc[fi][r];
    }
    __syncthreads();

    // kh=0 waves: combine halves, normalize, write sOh (bf16)
    if (kh == 0) {
        float linv[4];
        #pragma unroll
        for (int r = 0; r < 4; ++r) {
            int m16 = quad * 4 + r;
            linv[r] = 1.0f / (lws[msel * 16 + m16] + lws[(4 + msel) * 16 + m16]);
        }
        #pragma unroll
        for (int fi = 0; fi < 8; ++fi)
            #pragma unroll
            for (int r = 0; r < 4; ++r) {
                int row = msel * 16 + quad * 4 + r;
                float v = (oacc[fi][r] + pOx[row * POX_STRIDE + fi * 16 + c]) * linv[r];
                sOh[row * SOH_STRIDE + fi * 16 + c] = (bf16)v;
            }
    }
    __syncthreads();

    // stage O2^T: sO2t[f][f'] = O[h*128+f'][f] * dv[f']  (reuses pOx region)
    #pragma unroll
    for (int i = 0; i < 8; ++i) {
        int fp4 = grp * 32 + i * 4;
        bf16x4 w;
        #pragma unroll
        for (int j = 0; j < 4; ++j) {
            int x = fp4 + j;
            w[j] = (bf16)(Om[(h * F_ + x) * F_ + fv] * g_s[x]);
        }
        *(bf16x4*)(sO2t + fv * SO2_STRIDE + fp4) = w;
    }
    __syncthreads();

    // out_partial = Oh @ O2 : wave (pm = m-tile, pf = f-half)
    const int pm = wave & 3;
    const int pf = wave >> 2;
    bf16x8 afr[4];
    const bf16* ohrow = sOh + (pm * 16 + c) * SOH_STRIDE;
    #pragma unroll
    for (int kc = 0; kc < 4; ++kc)
        afr[kc] = *(const bf16x8*)(ohrow + kc * 32 + quad * 8);

    #pragma unroll
    for (int nt = 0; nt < 4; ++nt) {
        f32x4 pacc;
        #pragma unroll
        for (int r = 0; r < 4; ++r) pacc[r] = 0.f;
        const bf16* orow = sO2t + ((pf * 4 + nt) * 16 + c) * SO2_STRIDE;
        #pragma unroll
        for (int kc = 0; kc < 4; ++kc) {
            bf16x8 bfrag = *(const bf16x8*)(orow + kc * 32 + quad * 8);
            pacc = mfma32(afr[kc], bfrag, pacc);
        }
        #pragma unroll
        for (int r = 0; r < 4; ++r) {
            int qg = q0 + pm * 16 + quad * 4 + r;
            atomicAdd(out + ((size_t)(b * L_ + qg) * F_ + (pf * 4 + nt) * 16 + c), pacc[r]);
        }
    }
}

extern "C" void kernel_launch(void* const* d_in, const int* in_sizes, int n_in,
                              void* d_out, int out_size, void* d_ws, size_t ws_size,
                              hipStream_t stream) {
    const float* XQ   = (const float*)d_in[0];
    const float* XK   = (const float*)d_in[1];
    const float* XV   = (const float*)d_in[2];
    const int*   mask = (const int*)d_in[3];
    const float* WQ   = (const float*)d_in[4];
    const float* WK   = (const float*)d_in[5];
    const float* WV   = (const float*)d_in[6];
    const float* Om   = (const float*)d_in[7];
    float* out = (float*)d_out;

    char* ws = (char*)d_ws;
    bf16* Kb   = (bf16*)(ws + WS_KB);
    bf16* Vtb  = (bf16*)(ws + WS_VT);
    u64*  bits = (u64*)(ws + WS_MB);

    prep_one<<<2688, 256, 0, stream>>>(XK, XV, mask, Kb, Vtb, bits, out);

    dim3 grid(L_ / QT, H_, B_);
    attn_fused_kernel<<<grid, 512, 0, stream>>>(XQ, Kb, Vtb, bits, WQ, WK, WV, Om, out);
}

// Round 17
// 150.912 us; speedup vs baseline: 2.8700x; 1.0215x over previous
//
#include <hip/hip_runtime.h>

typedef __bf16 bf16;
typedef __bf16 bf16x4 __attribute__((ext_vector_type(4)));
typedef __bf16 bf16x8 __attribute__((ext_vector_type(8)));
typedef float f32x4 __attribute__((ext_vector_type(4)));
typedef short s16x4 __attribute__((ext_vector_type(4)));
typedef unsigned int u32;
typedef unsigned long long u64;

#define B_ 2
#define H_ 8
#define L_ 2048
#define D_ 128
#define F_ 128
#define QT 64
#define KT 64
#define NKT (L_ / KT)

// workspace layout (bytes)
#define WS_KB 0u            // Kb  : bf16 [b][k][16B-chunk swz], rows PERMUTED, 1 MB
#define WS_VT (1u << 20)    // Vtb : bf16 tiles [b][kt][f][8B-group swz], 1 MB
#define WS_MB (2u << 20)    // bits: u64 [b][q][kt], 1 MB

// LDS main: sK0@0 sK1@16384 sV0@32768 sV1@49152 (16KB each), lws@65536 (512B)
// epilogue: pOx@0 f32 [64][132] = 33792 ; sOh@36864 bf16 [64][136] = 17408 ;
//           sO2t@0 bf16 [128][136] = 34816 (after pOx reads done) ; lws kept.
#define SMEM_BYTES 66048
#define LWS_OFF 65536
#define POX_STRIDE 132
#define SOH_OFF 36864
#define SOH_STRIDE 136
#define SO2_STRIDE 136

__device__ __forceinline__ void dma16(const void* g, void* l) {
    __builtin_amdgcn_global_load_lds(
        (const __attribute__((address_space(1))) u32*)g,
        (__attribute__((address_space(3))) u32*)l, 16, 0, 0);
}

__device__ __forceinline__ f32x4 mfma32(bf16x8 a, bf16x8 b, f32x4 c) {
    return __builtin_amdgcn_mfma_f32_16x16x32_bf16(a, b, c, 0, 0, 0);
}

// guaranteed single-instruction exp2 (log2e is folded into g_s upstream)
__device__ __forceinline__ float fexp2(float x) {
#if __has_builtin(__builtin_amdgcn_exp2f)
    return __builtin_amdgcn_exp2f(x);
#else
    float r;
    asm("v_exp_f32 %0, %1" : "=v"(r) : "v"(x));
    return r;
#endif
}

// spread 16 bits to stride-4 positions of a u64 (bit i -> bit 4i)
__device__ __forceinline__ u64 spread4(u64 v) {
    v = (v | (v << 24)) & 0x000000ff000000ffULL;
    v = (v | (v << 12)) & 0x000f000f000f000fULL;
    v = (v | (v << 6))  & 0x0303030303030303ULL;
    v = (v | (v << 3))  & 0x1111111111111111ULL;
    return v;
}

// ---- SINGLE prep launch: mask bitpack (0..2047), K cvt+perm+swz (2048..2303),
//      V^T tiles (2304..2559), out zero (2560..2687).
// R9 falsified direct mask reads in attn; R12 falsified V-from-L2.
// R15: K rows are PERMUTED within each 64-row tile (k bits [5]=h [4:3]=quad
// [2]=t [1:0]=r  ->  row bits [5]=h [4]=t [3:2]=quad [1:0]=r) so the QK^T
// output lands directly in 16x16x32-A fragment layout (lane(c,quad) holds
// k=quad*8+j) -> PV runs as 8 mfma32 instead of 16 mfma16.
__global__ __launch_bounds__(256)
void prep_one(const float* __restrict__ XK, const float* __restrict__ XV,
              const int* __restrict__ mask, bf16* __restrict__ Kb,
              bf16* __restrict__ Vtb, u64* __restrict__ bits,
              float* __restrict__ out)
{
    const int bid = blockIdx.x;
    const int tid = threadIdx.x;
    if (bid < 2048) {
        // mask bitpack: wave-iter W handles 256 ints (16B/lane); 4 ballots +
        // stride-4 spread on lanes 0..3 rebuild bits[W*4+q] (R8-verified).
        const int lane = tid & 63;
        const int wv   = bid * 4 + (tid >> 6);     // 0..8191
        const int4* m4 = (const int4*)mask;
        #pragma unroll
        for (int t = 0; t < 4; ++t) {
            int W = wv + t * 8192;                 // 0..32767
            int4 v = m4[(size_t)W * 64 + lane];
            int nib = (v.x != 0 ? 1 : 0) | (v.y != 0 ? 2 : 0)
                    | (v.z != 0 ? 4 : 0) | (v.w != 0 ? 8 : 0);
            u64 b0 = __ballot(nib & 1);
            u64 b1 = __ballot(nib & 2);
            u64 b2 = __ballot(nib & 4);
            u64 b3 = __ballot(nib & 8);
            if (lane < 4) {
                int sh = lane * 16;
                u64 w = spread4((b0 >> sh) & 0xFFFFull)
                      | (spread4((b1 >> sh) & 0xFFFFull) << 1)
                      | (spread4((b2 >> sh) & 0xFFFFull) << 2)
                      | (spread4((b3 >> sh) & 0xFFFFull) << 3);
                bits[(size_t)W * 4 + lane] = w;
            }
        }
    } else if (bid < 2304) {
        int gid = (bid - 2048) * 256 + tid;
        int row = gid >> 4;                   // logical global k row (b*2048+k)
        int j   = gid & 15;
        const float* src = XK + (size_t)row * 128 + j * 8;
        float4 v0 = *(const float4*)src;
        float4 v1 = *(const float4*)(src + 4);
        bf16x8 w;
        w[0] = (bf16)v0.x; w[1] = (bf16)v0.y; w[2] = (bf16)v0.z; w[3] = (bf16)v0.w;
        w[4] = (bf16)v1.x; w[5] = (bf16)v1.y; w[6] = (bf16)v1.z; w[7] = (bf16)v1.w;
        // permute row within its 64-row tile (see header comment)
        int k63  = row & 63;
        int p63  = (k63 & 32) | ((k63 & 4) << 2) | ((k63 & 24) >> 1) | (k63 & 3);
        int prow = (row & ~63) | p63;
        int jp = j ^ (prow & 15);
        *(bf16x8*)(Kb + (size_t)prow * 128 + jp * 8) = w;
    } else if (bid < 2560) {
        // V^T tiles [tile][f][64k]; 8B group g (k=4g..4g+3) stored at g^(f&15)
        int idx  = bid - 2304;
        int tile = idx >> 2;
        int fq   = idx & 3;
        int f    = fq * 32 + (tid & 31);
        int j    = tid >> 5;                  // 0..7 -> k = 8j..8j+7
        int bb   = tile >> 5, kt = tile & 31;
        const float* src = XV + ((size_t)(bb * L_ + kt * 64 + j * 8)) * F_ + f;
        bf16x4 w0, w1;
        #pragma unroll
        for (int jj = 0; jj < 4; ++jj) {
            w0[jj] = (bf16)src[(size_t)jj * F_];
            w1[jj] = (bf16)src[(size_t)(4 + jj) * F_];
        }
        bf16* outp = Vtb + (size_t)tile * 8192 + f * 64;
        *(bf16x4*)(outp + (((2 * j) ^ (f & 15)) * 4)) = w0;
        *(bf16x4*)(outp + (((2 * j + 1) ^ (f & 15)) * 4)) = w1;
    } else {
        // zero out[] (B*L*F floats = 131072 float4), replaces hipMemsetAsync
        float4* o4 = (float4*)out;
        int idx = (bid - 2560) * 256 + tid;        // 0..32767
        float4 z; z.x = 0.f; z.y = 0.f; z.z = 0.f; z.w = 0.f;
        #pragma unroll
        for (int t = 0; t < 4; ++t) o4[idx + t * 32768] = z;
    }
}

// ---- main fused kernel: 512 threads / 8 waves; wave = (kh, msel) ----
// Geometry: 512 blocks, 2 blocks/CU (LDS-capped), 16 waves/CU (R10/R13 best).
// REGISTER-CAP RULE (R3/R4/R11): no launch_bounds 2nd arg, no waves_per_eu>4;
// (4,4) is the only safe attribute.
// R15: K-row permutation (in prep) makes the QK^T output = 16x16x32-A layout
// directly -> PV is 8 mfma32/iter (was 16 mfma16): 24 -> 16 MFMA issues/iter.
// tacc[t][r] now holds S^T for logical k = kh*32 + quad*8 + t*4 + r.
__global__ __launch_bounds__(512)
__attribute__((amdgpu_waves_per_eu(4, 4)))
void attn_fused_kernel(const float* __restrict__ XQ, const bf16* __restrict__ Kb,
                       const bf16* __restrict__ Vtb, const u64* __restrict__ bits,
                       const float* __restrict__ WQ, const float* __restrict__ WK,
                       const float* __restrict__ WV, const float* __restrict__ Om,
                       float* __restrict__ out)
{
    __shared__ __align__(16) char smem[SMEM_BYTES];
    __shared__ __align__(16) float g_s[128];

    bf16* sK0 = (bf16*)smem;
    bf16* sK1 = (bf16*)(smem + 16384);
    bf16* sV0 = (bf16*)(smem + 32768);
    bf16* sV1 = (bf16*)(smem + 49152);
    float* lws = (float*)(smem + LWS_OFF);
    float* pOx = (float*)smem;                 // epilogue
    bf16* sOh  = (bf16*)(smem + SOH_OFF);      // epilogue
    bf16* sO2t = (bf16*)smem;                  // epilogue (after pOx reads done)

    const int tid  = threadIdx.x;
    const int wave = tid >> 6;        // 0..7
    const int lane = tid & 63;
    const int c    = lane & 15;
    const int quad = lane >> 4;
    const int qt = blockIdx.x, h = blockIdx.y, b = blockIdx.z;
    const int q0 = qt * QT;

    const int kh   = wave >> 2;       // k-half (32 k)
    const int msel = wave & 3;        // m-tile (16 m)
    const int fv  = tid & 127;        // epilogue staging
    const int grp = tid >> 7;         // 0..3

    if (tid < 128) {
        float wq = WQ[(h * D_ + tid) * D_ + tid];
        float wk = WK[(h * D_ + tid) * D_ + tid];
        // fold softmax scale AND log2(e): exp becomes a raw v_exp_f32
        g_s[tid] = wq * wk * 0.08838834764831845f * 1.4426950408889634f;
    }
    __syncthreads();

    const char* gKbase = (const char*)Kb + (size_t)(b * L_) * 256;
    const char* gVbase = (const char*)Vtb + (size_t)(b * NKT) * 16384;

    // DMA tile 0
    #pragma unroll
    for (int i = 0; i < 2; ++i) dma16(gKbase + i * 8192 + tid * 16, (char*)sK0 + i * 8192 + tid * 16);
    #pragma unroll
    for (int i = 0; i < 2; ++i) dma16(gVbase + i * 8192 + tid * 16, (char*)sV0 + i * 8192 + tid * 16);

    const u64* mrow = bits + (size_t)(b * L_ + q0 + msel * 16 + c) * NKT;
    u64 mbc = mrow[0];                 // mask prefetch (one k-tile ahead)
    const int mshift = kh * 32 + quad * 8;   // wave-constant mask pre-shift (R15)

    // hoisted loop-invariant LDS byte offsets (statically indexed -> registers)
    int koff[2][4];
    #pragma unroll
    for (int kti = 0; kti < 2; ++kti)
        #pragma unroll
        for (int kc = 0; kc < 4; ++kc)
            koff[kti][kc] = ((((kh * 2 + kti) * 16 + c) * 128) + (((kc * 4 + quad) ^ c) * 8)) * 2;
    // V fragment offsets: B operand of 16x16x32 needs groups g0=kh*8+quad*2, g0+1
    int voff[8][2];
    #pragma unroll
    for (int fi = 0; fi < 8; ++fi)
        #pragma unroll
        for (int half = 0; half < 2; ++half) {
            int g = kh * 8 + quad * 2 + half;
            voff[fi][half] = (((fi * 16 + c) * 64) + ((g ^ c) * 4)) * 2;
        }

    // wave's Q m-tile as B-fragments (scaled by g, bf16), loop-invariant
    bf16x8 qfrag[4];
    {
        const float* qrow = XQ + (size_t)(b * L_ + q0 + msel * 16 + c) * D_;
        #pragma unroll
        for (int kc = 0; kc < 4; ++kc) {
            int d0 = kc * 32 + quad * 8;
            float4 v0 = *(const float4*)(qrow + d0);
            float4 v1 = *(const float4*)(qrow + d0 + 4);
            float4 g0 = *(const float4*)(g_s + d0);
            float4 g1 = *(const float4*)(g_s + d0 + 4);
            bf16x8 w;
            w[0] = (bf16)(v0.x * g0.x); w[1] = (bf16)(v0.y * g0.y);
            w[2] = (bf16)(v0.z * g0.z); w[3] = (bf16)(v0.w * g0.w);
            w[4] = (bf16)(v1.x * g1.x); w[5] = (bf16)(v1.y * g1.y);
            w[6] = (bf16)(v1.z * g1.z); w[7] = (bf16)(v1.w * g1.w);
            qfrag[kc] = w;
        }
    }

    f32x4 oacc[8];                     // partial O[m-tile msel][128 f] for kh's 32 k
    #pragma unroll
    for (int fi = 0; fi < 8; ++fi)
        #pragma unroll
        for (int r = 0; r < 4; ++r) oacc[fi][r] = 0.f;
    float lsum = 0.f;                  // per-lane: row m = msel*16+c, wave's k slice

    #pragma unroll 2
    for (int kt = 0; kt < NKT; ++kt) {
        const char* sK  = (kt & 1) ? (char*)sK1 : (char*)sK0;
        const char* sV  = (kt & 1) ? (char*)sV1 : (char*)sV0;
        bf16* sKn = (kt & 1) ? sK0 : sK1;
        bf16* sVn = (kt & 1) ? sV0 : sV1;

        // A: all waves done reading buf[next]
        asm volatile("s_barrier" ::: "memory");

        u64 mb = mbc;

        if (kt + 1 < NKT) {
            const char* gk = gKbase + (size_t)(kt + 1) * 16384;
            const char* gv = gVbase + (size_t)(kt + 1) * 16384;
            #pragma unroll
            for (int i = 0; i < 2; ++i) dma16(gk + i * 8192 + tid * 16, (char*)sKn + i * 8192 + tid * 16);
            #pragma unroll
            for (int i = 0; i < 2; ++i) dma16(gv + i * 8192 + tid * 16, (char*)sVn + i * 8192 + tid * 16);
            mbc = mrow[kt + 1];        // prefetch next tile's mask word
            // newest 5 = 1 mask + 4 next-DMA -> tile kt's DMA drained
            asm volatile("s_waitcnt vmcnt(5)" ::: "memory");
        } else {
            asm volatile("s_waitcnt vmcnt(0)" ::: "memory");
        }
        // B: tile kt resident
        asm volatile("s_barrier" ::: "memory");

        __builtin_amdgcn_s_setprio(1);

        // S^T = K @ Qg^T for wave's 2 physical k-row groups; due to the K-row
        // permutation, tacc[t][r] = S^T[logical k = kh*32+quad*8+t*4+r][m]
        f32x4 tacc[2];
        #pragma unroll
        for (int kti = 0; kti < 2; ++kti)
            #pragma unroll
            for (int r = 0; r < 4; ++r) tacc[kti][r] = 0.f;

        #pragma unroll
        for (int kti = 0; kti < 2; ++kti) {
            #pragma unroll
            for (int kc = 0; kc < 4; ++kc) {
                bf16x8 kfrag = *(const bf16x8*)(sK + koff[kti][kc]);
                tacc[kti] = mfma32(kfrag, qfrag[kc], tacc[kti]);
            }
        }

        // exp2 + mask -> apack = 16x16x32 A-fragment: apack[j] = P[k=quad*8+j]
        bf16x8 apack;
        #pragma unroll
        for (int kti = 0; kti < 2; ++kti) {
            #pragma unroll
            for (int r = 0; r < 4; ++r) {
                float p = ((mb >> (mshift + kti * 4 + r)) & 1ull)
                          ? fexp2(tacc[kti][r]) : 0.f;
                lsum += p;
                apack[kti * 4 + r] = (bf16)p;
            }
        }

        // O_partial += P @ V over wave's 32 k: 8 mfma32 (was 16 mfma16)
        #pragma unroll
        for (int fi = 0; fi < 8; ++fi) {
            bf16x4 vlo = *(const bf16x4*)(sV + voff[fi][0]);
            bf16x4 vhi = *(const bf16x4*)(sV + voff[fi][1]);
            bf16x8 v8;
            #pragma unroll
            for (int r = 0; r < 4; ++r) { v8[r] = vlo[r]; v8[4 + r] = vhi[r]; }
            oacc[fi] = mfma32(apack, v8, oacc[fi]);
        }

        __builtin_amdgcn_s_setprio(0);
    }

    // publish per-wave row sums: lane c holds sum over wave's 32k after quad-reduce
    {
        float v = lsum;
        v += __shfl_xor(v, 16); v += __shfl_xor(v, 32);
        if (lane < 16) lws[wave * 16 + lane] = v;
    }
    if (tid < 128)
        g_s[tid] = WV[(h * F_ + tid) * F_ + tid];   // dv (g_s no longer needed)
    __syncthreads();   // main-loop LDS reads done; lws visible

    // kh=1 waves dump partial O to pOx
    if (kh == 1) {
        #pragma unroll
        for (int fi = 0; fi < 8; ++fi)
            #pragma unroll
            for (int r = 0; r < 4; ++r)
                pOx[(msel * 16 + quad * 4 + r) * POX_STRIDE + fi * 16 + c] = oacc[fi][r];
    }
    __syncthreads();

    // kh=0 waves: combine halves, normalize, write sOh (bf16)
    if (kh == 0) {
        float linv[4];
        #pragma unroll
        for (int r = 0; r < 4; ++r) {
            int m16 = quad * 4 + r;
            linv[r] = 1.0f / (lws[msel * 16 + m16] + lws[(4 + msel) * 16 + m16]);
        }
        #pragma unroll
        for (int fi = 0; fi < 8; ++fi)
            #pragma unroll
            for (int r = 0; r < 4; ++r) {
                int row = msel * 16 + quad * 4 + r;
                float v = (oacc[fi][r] + pOx[row * POX_STRIDE + fi * 16 + c]) * linv[r];
                sOh[row * SOH_STRIDE + fi * 16 + c] = (bf16)v;
            }
    }
    __syncthreads();

    // stage O2^T: sO2t[f][f'] = O[h*128+f'][f] * dv[f']  (reuses pOx region)
    #pragma unroll
    for (int i = 0; i < 8; ++i) {
        int fp4 = grp * 32 + i * 4;
        bf16x4 w;
        #pragma unroll
        for (int j = 0; j < 4; ++j) {
            int x = fp4 + j;
            w[j] = (bf16)(Om[(h * F_ + x) * F_ + fv] * g_s[x]);
        }
        *(bf16x4*)(sO2t + fv * SO2_STRIDE + fp4) = w;
    }
    __syncthreads();

    // out_partial = Oh @ O2 : wave (pm = m-tile, pf = f-half)
    const int pm = wave & 3;
    const int pf = wave >> 2;
    bf16x8 afr[4];
    const bf16* ohrow = sOh + (pm * 16 + c) * SOH_STRIDE;
    #pragma unroll
    for (int kc = 0; kc < 4; ++kc)
        afr[kc] = *(const bf16x8*)(ohrow + kc * 32 + quad * 8);

    #pragma unroll
    for (int nt = 0; nt < 4; ++nt) {
        f32x4 pacc;
        #pragma unroll
        for (int r = 0; r < 4; ++r) pacc[r] = 0.f;
        const bf16* orow = sO2t + ((pf * 4 + nt) * 16 + c) * SO2_STRIDE;
        #pragma unroll
        for (int kc = 0; kc < 4; ++kc) {
            bf16x8 bfrag = *(const bf16x8*)(orow + kc * 32 + quad * 8);
            pacc = mfma32(afr[kc], bfrag, pacc);
        }
        #pragma unroll
        for (int r = 0; r < 4; ++r) {
            int qg = q0 + pm * 16 + quad * 4 + r;
            atomicAdd(out + ((size_t)(b * L_ + qg) * F_ + (pf * 4 + nt) * 16 + c), pacc[r]);
        }
    }
}

extern "C" void kernel_launch(void* const* d_in, const int* in_sizes, int n_in,
                              void* d_out, int out_size, void* d_ws, size_t ws_size,
                              hipStream_t stream) {
    const float* XQ   = (const float*)d_in[0];
    const float* XK   = (const float*)d_in[1];
    const float* XV   = (const float*)d_in[2];
    const int*   mask = (const int*)d_in[3];
    const float* WQ   = (const float*)d_in[4];
    const float* WK   = (const float*)d_in[5];
    const float* WV   = (const float*)d_in[6];
    const float* Om   = (const float*)d_in[7];
    float* out = (float*)d_out;

    char* ws = (char*)d_ws;
    bf16* Kb   = (bf16*)(ws + WS_KB);
    bf16* Vtb  = (bf16*)(ws + WS_VT);
    u64*  bits = (u64*)(ws + WS_MB);

    prep_one<<<2688, 256, 0, stream>>>(XK, XV, mask, Kb, Vtb, bits, out);

    dim3 grid(L_ / QT, H_, B_);
    attn_fused_kernel<<<grid, 512, 0, stream>>>(XQ, Kb, Vtb, bits, WQ, WK, WV, Om, out);
}

// Round 20
// 150.592 us; speedup vs baseline: 2.8761x; 1.0021x over previous
//
#include <hip/hip_runtime.h>

typedef __bf16 bf16;
typedef __bf16 bf16x4 __attribute__((ext_vector_type(4)));
typedef __bf16 bf16x8 __attribute__((ext_vector_type(8)));
typedef float f32x4 __attribute__((ext_vector_type(4)));
typedef short s16x4 __attribute__((ext_vector_type(4)));
typedef unsigned int u32;
typedef unsigned long long u64;

#define B_ 2
#define H_ 8
#define L_ 2048
#define D_ 128
#define F_ 128
#define QT 64
#define KT 64
#define NKT (L_ / KT)

// workspace layout (bytes)
#define WS_KB 0u            // Kb  : bf16 [b][k][16B-chunk swz], rows PERMUTED, 1 MB
#define WS_VT (1u << 20)    // Vtb : bf16 tiles [b][kt][f][k-octet swz, 16B], 1 MB
#define WS_MB (2u << 20)    // bits: u64 [b][q][kt], 1 MB

// LDS main: sK0@0 sK1@16384 sV0@32768 sV1@49152 (16KB each), lws@65536 (512B)
// epilogue: pOx@0 f32 [64][132] = 33792 ; sOh@36864 bf16 [64][136] = 17408 ;
//           sO2t@0 bf16 [128][136] = 34816 (after pOx reads done) ; lws kept.
#define SMEM_BYTES 66048
#define LWS_OFF 65536
#define POX_STRIDE 132
#define SOH_OFF 36864
#define SOH_STRIDE 136
#define SO2_STRIDE 136

__device__ __forceinline__ void dma16(const void* g, void* l) {
    __builtin_amdgcn_global_load_lds(
        (const __attribute__((address_space(1))) u32*)g,
        (__attribute__((address_space(3))) u32*)l, 16, 0, 0);
}

__device__ __forceinline__ f32x4 mfma32(bf16x8 a, bf16x8 b, f32x4 c) {
    return __builtin_amdgcn_mfma_f32_16x16x32_bf16(a, b, c, 0, 0, 0);
}

// guaranteed single-instruction exp2 (log2e is folded into g_s upstream)
__device__ __forceinline__ float fexp2(float x) {
#if __has_builtin(__builtin_amdgcn_exp2f)
    return __builtin_amdgcn_exp2f(x);
#else
    float r;
    asm("v_exp_f32 %0, %1" : "=v"(r) : "v"(x));
    return r;
#endif
}

// spread 16 bits to stride-4 positions of a u64 (bit i -> bit 4i)
__device__ __forceinline__ u64 spread4(u64 v) {
    v = (v | (v << 24)) & 0x000000ff000000ffULL;
    v = (v | (v << 12)) & 0x000f000f000f000fULL;
    v = (v | (v << 6))  & 0x0303030303030303ULL;
    v = (v | (v << 3))  & 0x1111111111111111ULL;
    return v;
}

// ---- SINGLE prep launch: mask bitpack (0..2047), K cvt+perm+swz (2048..2303),
//      V octet tiles (2304..2559), out zero (2560..2687).
// R9 falsified direct mask reads; R12 falsified V-from-L2.
// R15 (validated R17, -1.5us): K rows PERMUTED within each 64-row tile so QK^T
// output = 16x16x32-A fragment -> PV is 8 mfma32.
// R18: V stored as 16B k-OCTETS: [tile][f][gg=k>>3 swz gg^(f&7)][8 bf16] ->
// attn reads ONE ds_read_b128 per fi (was 2x b64 + operand assembly).
__global__ __launch_bounds__(256)
void prep_one(const float* __restrict__ XK, const float* __restrict__ XV,
              const int* __restrict__ mask, bf16* __restrict__ Kb,
              bf16* __restrict__ Vtb, u64* __restrict__ bits,
              float* __restrict__ out)
{
    const int bid = blockIdx.x;
    const int tid = threadIdx.x;
    if (bid < 2048) {
        // mask bitpack: wave-iter W handles 256 ints (16B/lane); 4 ballots +
        // stride-4 spread on lanes 0..3 rebuild bits[W*4+q] (R8-verified).
        const int lane = tid & 63;
        const int wv   = bid * 4 + (tid >> 6);     // 0..8191
        const int4* m4 = (const int4*)mask;
        #pragma unroll
        for (int t = 0; t < 4; ++t) {
            int W = wv + t * 8192;                 // 0..32767
            int4 v = m4[(size_t)W * 64 + lane];
            int nib = (v.x != 0 ? 1 : 0) | (v.y != 0 ? 2 : 0)
                    | (v.z != 0 ? 4 : 0) | (v.w != 0 ? 8 : 0);
            u64 b0 = __ballot(nib & 1);
            u64 b1 = __ballot(nib & 2);
            u64 b2 = __ballot(nib & 4);
            u64 b3 = __ballot(nib & 8);
            if (lane < 4) {
                int sh = lane * 16;
                u64 w = spread4((b0 >> sh) & 0xFFFFull)
                      | (spread4((b1 >> sh) & 0xFFFFull) << 1)
                      | (spread4((b2 >> sh) & 0xFFFFull) << 2)
                      | (spread4((b3 >> sh) & 0xFFFFull) << 3);
                bits[(size_t)W * 4 + lane] = w;
            }
        }
    } else if (bid < 2304) {
        int gid = (bid - 2048) * 256 + tid;
        int row = gid >> 4;                   // logical global k row (b*2048+k)
        int j   = gid & 15;
        const float* src = XK + (size_t)row * 128 + j * 8;
        float4 v0 = *(const float4*)src;
        float4 v1 = *(const float4*)(src + 4);
        bf16x8 w;
        w[0] = (bf16)v0.x; w[1] = (bf16)v0.y; w[2] = (bf16)v0.z; w[3] = (bf16)v0.w;
        w[4] = (bf16)v1.x; w[5] = (bf16)v1.y; w[6] = (bf16)v1.z; w[7] = (bf16)v1.w;
        // permute row within its 64-row tile (k bits h,quad,t,r -> h,t,quad,r)
        int k63  = row & 63;
        int p63  = (k63 & 32) | ((k63 & 4) << 2) | ((k63 & 24) >> 1) | (k63 & 3);
        int prow = (row & ~63) | p63;
        int jp = j ^ (prow & 15);
        *(bf16x8*)(Kb + (size_t)prow * 128 + jp * 8) = w;
    } else if (bid < 2560) {
        // V octet tiles: [tile][f][gg^(f&7)][8 bf16]; octet gg=j covers k=8j..8j+7
        int idx  = bid - 2304;
        int tile = idx >> 2;
        int fq   = idx & 3;
        int f    = fq * 32 + (tid & 31);
        int j    = tid >> 5;                  // 0..7 -> k = 8j..8j+7
        int bb   = tile >> 5, kt = tile & 31;
        const float* src = XV + ((size_t)(bb * L_ + kt * 64 + j * 8)) * F_ + f;
        bf16x8 w;
        #pragma unroll
        for (int jj = 0; jj < 8; ++jj)
            w[jj] = (bf16)src[(size_t)jj * F_];
        bf16* outp = Vtb + (size_t)tile * 8192 + f * 64;
        *(bf16x8*)(outp + ((j ^ (f & 7)) * 8)) = w;
    } else {
        // zero out[] (B*L*F floats = 131072 float4), replaces hipMemsetAsync
        float4* o4 = (float4*)out;
        int idx = (bid - 2560) * 256 + tid;        // 0..32767
        float4 z; z.x = 0.f; z.y = 0.f; z.z = 0.f; z.w = 0.f;
        #pragma unroll
        for (int t = 0; t < 4; ++t) o4[idx + t * 32768] = z;
    }
}

// ---- main fused kernel: 512 threads / 8 waves; wave = (kh, msel) ----
// Geometry: 512 blocks, 2 blocks/CU (LDS-capped), 16 waves/CU.
// REGISTER-CAP RULE (R3/R4/R11): no launch_bounds 2nd arg, no waves_per_eu>4;
// (4,4) is the only safe attribute.
// R15 (validated): K-row perm -> PV = 8 mfma32/iter. R18: V b128 octet reads
// (8 ds_read_b128/iter, was 16 ds_read_b64 + operand assembly).
__global__ __launch_bounds__(512)
__attribute__((amdgpu_waves_per_eu(4, 4)))
void attn_fused_kernel(const float* __restrict__ XQ, const bf16* __restrict__ Kb,
                       const bf16* __restrict__ Vtb, const u64* __restrict__ bits,
                       const float* __restrict__ WQ, const float* __restrict__ WK,
                       const float* __restrict__ WV, const float* __restrict__ Om,
                       float* __restrict__ out)
{
    __shared__ __align__(16) char smem[SMEM_BYTES];
    __shared__ __align__(16) float g_s[128];

    bf16* sK0 = (bf16*)smem;
    bf16* sK1 = (bf16*)(smem + 16384);
    bf16* sV0 = (bf16*)(smem + 32768);
    bf16* sV1 = (bf16*)(smem + 49152);
    float* lws = (float*)(smem + LWS_OFF);
    float* pOx = (float*)smem;                 // epilogue
    bf16* sOh  = (bf16*)(smem + SOH_OFF);      // epilogue
    bf16* sO2t = (bf16*)smem;                  // epilogue (after pOx reads done)

    const int tid  = threadIdx.x;
    const int wave = tid >> 6;        // 0..7
    const int lane = tid & 63;
    const int c    = lane & 15;
    const int quad = lane >> 4;
    const int qt = blockIdx.x, h = blockIdx.y, b = blockIdx.z;
    const int q0 = qt * QT;

    const int kh   = wave >> 2;       // k-half (32 k)
    const int msel = wave & 3;        // m-tile (16 m)
    const int fv  = tid & 127;        // epilogue staging
    const int grp = tid >> 7;         // 0..3

    if (tid < 128) {
        float wq = WQ[(h * D_ + tid) * D_ + tid];
        float wk = WK[(h * D_ + tid) * D_ + tid];
        // fold softmax scale AND log2(e): exp becomes a raw v_exp_f32
        g_s[tid] = wq * wk * 0.08838834764831845f * 1.4426950408889634f;
    }
    __syncthreads();

    const char* gKbase = (const char*)Kb + (size_t)(b * L_) * 256;
    const char* gVbase = (const char*)Vtb + (size_t)(b * NKT) * 16384;

    // DMA tile 0
    #pragma unroll
    for (int i = 0; i < 2; ++i) dma16(gKbase + i * 8192 + tid * 16, (char*)sK0 + i * 8192 + tid * 16);
    #pragma unroll
    for (int i = 0; i < 2; ++i) dma16(gVbase + i * 8192 + tid * 16, (char*)sV0 + i * 8192 + tid * 16);

    const u64* mrow = bits + (size_t)(b * L_ + q0 + msel * 16 + c) * NKT;
    u64 mbc = mrow[0];                 // mask prefetch (one k-tile ahead)
    const int mshift = kh * 32 + quad * 8;   // wave-constant mask pre-shift

    // hoisted loop-invariant LDS byte offsets (statically indexed -> registers)
    int koff[2][4];
    #pragma unroll
    for (int kti = 0; kti < 2; ++kti)
        #pragma unroll
        for (int kc = 0; kc < 4; ++kc)
            koff[kti][kc] = ((((kh * 2 + kti) * 16 + c) * 128) + (((kc * 4 + quad) ^ c) * 8)) * 2;
    // V octet offsets: octet gg = kh*4+quad, swizzled gg^(c&7), 16B units
    int voff[8];
    {
        int gg = kh * 4 + quad;
        #pragma unroll
        for (int fi = 0; fi < 8; ++fi)
            voff[fi] = ((fi * 16 + c) * 64 + ((gg ^ (c & 7)) * 8)) * 2;
    }

    // wave's Q m-tile as B-fragments (scaled by g, bf16), loop-invariant
    bf16x8 qfrag[4];
    {
        const float* qrow = XQ + (size_t)(b * L_ + q0 + msel * 16 + c) * D_;
        #pragma unroll
        for (int kc = 0; kc < 4; ++kc) {
            int d0 = kc * 32 + quad * 8;
            float4 v0 = *(const float4*)(qrow + d0);
            float4 v1 = *(const float4*)(qrow + d0 + 4);
            float4 g0 = *(const float4*)(g_s + d0);
            float4 g1 = *(const float4*)(g_s + d0 + 4);
            bf16x8 w;
            w[0] = (bf16)(v0.x * g0.x); w[1] = (bf16)(v0.y * g0.y);
            w[2] = (bf16)(v0.z * g0.z); w[3] = (bf16)(v0.w * g0.w);
            w[4] = (bf16)(v1.x * g1.x); w[5] = (bf16)(v1.y * g1.y);
            w[6] = (bf16)(v1.z * g1.z); w[7] = (bf16)(v1.w * g1.w);
            qfrag[kc] = w;
        }
    }

    f32x4 oacc[8];                     // partial O[m-tile msel][128 f] for kh's 32 k
    #pragma unroll
    for (int fi = 0; fi < 8; ++fi)
        #pragma unroll
        for (int r = 0; r < 4; ++r) oacc[fi][r] = 0.f;
    float lsum = 0.f;                  // per-lane: row m = msel*16+c, wave's k slice

    #pragma unroll 2
    for (int kt = 0; kt < NKT; ++kt) {
        const char* sK  = (kt & 1) ? (char*)sK1 : (char*)sK0;
        const char* sV  = (kt & 1) ? (char*)sV1 : (char*)sV0;
        bf16* sKn = (kt & 1) ? sK0 : sK1;
        bf16* sVn = (kt & 1) ? sV0 : sV1;

        // A: all waves done reading buf[next]
        asm volatile("s_barrier" ::: "memory");

        u64 mb = mbc;

        if (kt + 1 < NKT) {
            const char* gk = gKbase + (size_t)(kt + 1) * 16384;
            const char* gv = gVbase + (size_t)(kt + 1) * 16384;
            #pragma unroll
            for (int i = 0; i < 2; ++i) dma16(gk + i * 8192 + tid * 16, (char*)sKn + i * 8192 + tid * 16);
            #pragma unroll
            for (int i = 0; i < 2; ++i) dma16(gv + i * 8192 + tid * 16, (char*)sVn + i * 8192 + tid * 16);
            mbc = mrow[kt + 1];        // prefetch next tile's mask word
            // newest 5 = 1 mask + 4 next-DMA -> tile kt's DMA drained
            asm volatile("s_waitcnt vmcnt(5)" ::: "memory");
        } else {
            asm volatile("s_waitcnt vmcnt(0)" ::: "memory");
        }
        // B: tile kt resident
        asm volatile("s_barrier" ::: "memory");

        __builtin_amdgcn_s_setprio(1);

        // S^T = K @ Qg^T; via the K-row permutation,
        // tacc[t][r] = S^T[logical k = kh*32+quad*8+t*4+r][m]
        f32x4 tacc[2];
        #pragma unroll
        for (int kti = 0; kti < 2; ++kti)
            #pragma unroll
            for (int r = 0; r < 4; ++r) tacc[kti][r] = 0.f;

        #pragma unroll
        for (int kti = 0; kti < 2; ++kti) {
            #pragma unroll
            for (int kc = 0; kc < 4; ++kc) {
                bf16x8 kfrag = *(const bf16x8*)(sK + koff[kti][kc]);
                tacc[kti] = mfma32(kfrag, qfrag[kc], tacc[kti]);
            }
        }

        // exp2 + mask -> apack = 16x16x32 A-fragment: apack[j] = P[k=quad*8+j]
        bf16x8 apack;
        #pragma unroll
        for (int kti = 0; kti < 2; ++kti) {
            #pragma unroll
            for (int r = 0; r < 4; ++r) {
                float p = ((mb >> (mshift + kti * 4 + r)) & 1ull)
                          ? fexp2(tacc[kti][r]) : 0.f;
                lsum += p;
                apack[kti * 4 + r] = (bf16)p;
            }
        }

        // O_partial += P @ V over wave's 32 k: 8 mfma32, one b128 V read each
        #pragma unroll
        for (int fi = 0; fi < 8; ++fi) {
            bf16x8 v8 = *(const bf16x8*)(sV + voff[fi]);
            oacc[fi] = mfma32(apack, v8, oacc[fi]);
        }

        __builtin_amdgcn_s_setprio(0);
    }

    // publish per-wave row sums: lane c holds sum over wave's 32k after quad-reduce
    {
        float v = lsum;
        v += __shfl_xor(v, 16); v += __shfl_xor(v, 32);
        if (lane < 16) lws[wave * 16 + lane] = v;
    }
    if (tid < 128)
        g_s[tid] = WV[(h * F_ + tid) * F_ + tid];   // dv (g_s no longer needed)
    __syncthreads();   // main-loop LDS reads done; lws visible

    // kh=1 waves dump partial O to pOx
    if (kh == 1) {
        #pragma unroll
        for (int fi = 0; fi < 8; ++fi)
            #pragma unroll
            for (int r = 0; r < 4; ++r)
                pOx[(msel * 16 + quad * 4 + r) * POX_STRIDE + fi * 16 + c] = oacc[fi][r];
    }
    __syncthreads();

    // kh=0 waves: combine halves, normalize, write sOh (bf16)
    if (kh == 0) {
        float linv[4];
        #pragma unroll
        for (int r = 0; r < 4; ++r) {
            int m16 = quad * 4 + r;
            linv[r] = 1.0f / (lws[msel * 16 + m16] + lws[(4 + msel) * 16 + m16]);
        }
        #pragma unroll
        for (int fi = 0; fi < 8; ++fi)
            #pragma unroll
            for (int r = 0; r < 4; ++r) {
                int row = msel * 16 + quad * 4 + r;
                float v = (oacc[fi][r] + pOx[row * POX_STRIDE + fi * 16 + c]) * linv[r];
                sOh[row * SOH_STRIDE + fi * 16 + c] = (bf16)v;
            }
    }
    __syncthreads();

    // stage O2^T: sO2t[f][f'] = O[h*128+f'][f] * dv[f']  (reuses pOx region)
    #pragma unroll
    for (int i = 0; i < 8; ++i) {
        int fp4 = grp * 32 + i * 4;
        bf16x4 w;
        #pragma unroll
        for (int j = 0; j < 4; ++j) {
            int x = fp4 + j;
            w[j] = (bf16)(Om[(h * F_ + x) * F_ + fv] * g_s[x]);
        }
        *(bf16x4*)(sO2t + fv * SO2_STRIDE + fp4) = w;
    }
    __syncthreads();

    // out_partial = Oh @ O2 : wave (pm = m-tile, pf = f-half)
    const int pm = wave & 3;
    const int pf = wave >> 2;
    bf16x8 afr[4];
    const bf16* ohrow = sOh + (pm * 16 + c) * SOH_STRIDE;
    #pragma unroll
    for (int kc = 0; kc < 4; ++kc)
        afr[kc] = *(const bf16x8*)(ohrow + kc * 32 + quad * 8);

    #pragma unroll
    for (int nt = 0; nt < 4; ++nt) {
        f32x4 pacc;
        #pragma unroll
        for (int r = 0; r < 4; ++r) pacc[r] = 0.f;
        const bf16* orow = sO2t + ((pf * 4 + nt) * 16 + c) * SO2_STRIDE;
        #pragma unroll
        for (int kc = 0; kc < 4; ++kc) {
            bf16x8 bfrag = *(const bf16x8*)(orow + kc * 32 + quad * 8);
            pacc = mfma32(afr[kc], bfrag, pacc);
        }
        #pragma unroll
        for (int r = 0; r < 4; ++r) {
            int qg = q0 + pm * 16 + quad * 4 + r;
            atomicAdd(out + ((size_t)(b * L_ + qg) * F_ + (pf * 4 + nt) * 16 + c), pacc[r]);
        }
    }
}

extern "C" void kernel_launch(void* const* d_in, const int* in_sizes, int n_in,
                              void* d_out, int out_size, void* d_ws, size_t ws_size,
                              hipStream_t stream) {
    const float* XQ   = (const float*)d_in[0];
    const float* XK   = (const float*)d_in[1];
    const float* XV   = (const float*)d_in[2];
    const int*   mask = (const int*)d_in[3];
    const float* WQ   = (const float*)d_in[4];
    const float* WK   = (const float*)d_in[5];
    const float* WV   = (const float*)d_in[6];
    const float* Om   = (const float*)d_in[7];
    float* out = (float*)d_out;

    char* ws = (char*)d_ws;
    bf16* Kb   = (bf16*)(ws + WS_KB);
    bf16* Vtb  = (bf16*)(ws + WS_VT);
    u64*  bits = (u64*)(ws + WS_MB);

    prep_one<<<2688, 256, 0, stream>>>(XK, XV, mask, Kb, Vtb, bits, out);

    dim3 grid(L_ / QT, H_, B_);
    attn_fused_kernel<<<grid, 512, 0, stream>>>(XQ, Kb, Vtb, bits, WQ, WK, WV, Om, out);
}